// Round 1
// baseline (1029.934 us; speedup 1.0000x reference)
//
#include <hip/hip_runtime.h>
#include <hip/hip_bf16.h>

// ---------------------------------------------------------------------------
// GATv2 model pipeline, fp32, multi-kernel. N=50000, E=400000, HID=64, H=8.
// ---------------------------------------------------------------------------

#define CDIV(a, b) (((a) + (b) - 1) / (b))

// out[n][c] = sum_k X[n][k]*W[k][64c] + b[c], one thread per output element.
__global__ void k_rowmm64(const float* __restrict__ X, const float* __restrict__ W,
                          const float* __restrict__ b, float* __restrict__ out,
                          int N, int K) {
    int idx = blockIdx.x * blockDim.x + threadIdx.x;
    int total = N * 64;
    if (idx >= total) return;
    int n = idx >> 6, c = idx & 63;
    const float* xr = X + (size_t)n * K;
    float acc = b[c];
    for (int k = 0; k < K; ++k) acc = fmaf(xr[k], W[k * 64 + c], acc);
    out[idx] = acc;
}

// Per edge (one wave): ef = edge_attr@W_ep + b_ep; atomic scatter onto dst.
__global__ void k_ef(const float* __restrict__ EA, const int* __restrict__ ei,
                     const float* __restrict__ W, const float* __restrict__ b,
                     float* __restrict__ aggsum, float* __restrict__ cnt, int E) {
    int wid = (blockIdx.x * blockDim.x + threadIdx.x) >> 6;
    int lane = threadIdx.x & 63;
    if (wid >= E) return;
    int col = ei[E + wid];                 // edge_index[1][e] = dst
    const float* e = EA + (size_t)wid * 16;
    float acc = b[lane];
#pragma unroll
    for (int k = 0; k < 16; ++k) acc = fmaf(e[k], W[k * 64 + lane], acc);
    atomicAdd(&aggsum[(size_t)col * 64 + lane], acc);
    if (lane == 0) atomicAdd(&cnt[col], 1.0f);
}

// Per node (one wave): agg = aggsum/max(cnt,1) (in place); z = (atom+agg)@W_msg + b.
__global__ void k_msg(const float* __restrict__ atomb, float* __restrict__ agg,
                      const float* __restrict__ cnt, const float* __restrict__ Wm,
                      const float* __restrict__ bm, float* __restrict__ z, int N) {
    int wid = (blockIdx.x * blockDim.x + threadIdx.x) >> 6;
    int lane = threadIdx.x & 63;
    if (wid >= N) return;
    size_t base = (size_t)wid * 64;
    float inv = 1.0f / fmaxf(cnt[wid], 1.0f);
    float a = agg[base + lane] * inv;
    agg[base + lane] = a;
    float tv = atomb[base + lane] + a;
    float acc = bm[lane];
    for (int k = 0; k < 64; ++k) {
        float tk = __shfl(tv, k, 64);
        acc = fmaf(tk, Wm[k * 64 + lane], acc);
    }
    z[base + lane] = acc;
}

// Per-channel sum & sumsq over rows. sums[0..C)=sum, sums[C..2C)=sumsq.
// Launch with gridDim.x*blockDim.x a multiple of C.
__global__ void k_stats(const float* __restrict__ X, float* __restrict__ sums,
                        int N, int C) {
    int t = blockIdx.x * blockDim.x + threadIdx.x;
    int c = t % C;
    int slice = t / C;
    int nslices = (gridDim.x * blockDim.x) / C;
    float ls = 0.f, lq = 0.f;
    for (int n = slice; n < N; n += nslices) {
        float v = X[(size_t)n * C + c];
        ls += v; lq += v * v;
    }
    atomicAdd(&sums[c], ls);
    atomicAdd(&sums[C + c], lq);
}

// Exclusive prefix sum of cnt (float counts) -> rowptr[N+1]. Single block.
__global__ void k_scan(const float* __restrict__ cnt, int* __restrict__ rowptr, int N) {
    __shared__ int buf[1024];
    __shared__ int carry;
    if (threadIdx.x == 0) { carry = 0; rowptr[0] = 0; }
    __syncthreads();
    for (int base = 0; base < N; base += 1024) {
        int i = base + threadIdx.x;
        int v = (i < N) ? (int)cnt[i] : 0;
        buf[threadIdx.x] = v;
        __syncthreads();
        for (int off = 1; off < 1024; off <<= 1) {
            int t = 0;
            if ((int)threadIdx.x >= off) t = buf[threadIdx.x - off];
            __syncthreads();
            buf[threadIdx.x] += t;
            __syncthreads();
        }
        if (i < N) rowptr[i + 1] = carry + buf[threadIdx.x];
        __syncthreads();
        if (threadIdx.x == 0) carry += buf[1023];
        __syncthreads();
    }
}

// Scatter edge sources into CSR order (order within a segment is arbitrary).
__global__ void k_fill(const int* __restrict__ ei, const int* __restrict__ rowptr,
                       int* __restrict__ cursor, int* __restrict__ esrc, int E) {
    int e = blockIdx.x * blockDim.x + threadIdx.x;
    if (e >= E) return;
    int dst = ei[E + e];
    int pos = rowptr[dst] + atomicAdd(&cursor[dst], 1);
    esrc[pos] = ei[e];
}

// comb = [relu(bn(z)), agg]  (built in LDS on the fly), then
// xl = comb@W_l, xr = comb@W_r.  Block: 32 rows x 256 cols; grid.y in 0..3.
__global__ __launch_bounds__(256) void k_xlxr(
    const float* __restrict__ z, const float* __restrict__ agg,
    const float* __restrict__ Wl, const float* __restrict__ Wr,
    const float* __restrict__ stats, const float* __restrict__ g,
    const float* __restrict__ be, float* __restrict__ xl,
    float* __restrict__ xr, int N) {
    __shared__ float comb[32][128];
    int rowbase = blockIdx.x * 32;
    int t = threadIdx.x;
    float invN = 1.0f / (float)N;
    for (int i = t; i < 32 * 128; i += 256) {
        int r = i >> 7, k = i & 127;
        int n = rowbase + r;
        float v = 0.f;
        if (n < N) {
            if (k < 64) {
                float mean = stats[k] * invN;
                float var = stats[64 + k] * invN - mean * mean;
                float inv = rsqrtf(var + 1e-5f);
                float val = (z[(size_t)n * 64 + k] - mean) * (inv * g[k]) + be[k];
                v = fmaxf(val, 0.f);
            } else {
                v = agg[(size_t)n * 64 + (k - 64)];
            }
        }
        comb[r][k] = v;
    }
    __syncthreads();
    const float* W = (blockIdx.y < 2) ? Wl : Wr;
    float* out = (blockIdx.y < 2) ? xl : xr;
    int cb = (blockIdx.y & 1) * 256;
    int lane = t & 63;
    int w = t >> 6;
    float acc[8][4];
#pragma unroll
    for (int r = 0; r < 8; ++r)
#pragma unroll
        for (int j = 0; j < 4; ++j) acc[r][j] = 0.f;
    for (int k4 = 0; k4 < 32; ++k4) {
        float bv[4][4];
#pragma unroll
        for (int kk = 0; kk < 4; ++kk)
#pragma unroll
            for (int j = 0; j < 4; ++j)
                bv[kk][j] = W[(size_t)(k4 * 4 + kk) * 512 + cb + j * 64 + lane];
#pragma unroll
        for (int r = 0; r < 8; ++r) {
            float4 a4 = *(const float4*)&comb[w * 8 + r][k4 * 4];
            float av[4] = {a4.x, a4.y, a4.z, a4.w};
#pragma unroll
            for (int kk = 0; kk < 4; ++kk)
#pragma unroll
                for (int j = 0; j < 4; ++j)
                    acc[r][j] = fmaf(av[kk], bv[kk][j], acc[r][j]);
        }
    }
#pragma unroll
    for (int r = 0; r < 8; ++r) {
        int n = rowbase + w * 8 + r;
        if (n < N) {
#pragma unroll
            for (int j = 0; j < 4; ++j)
                out[(size_t)n * 512 + cb + j * 64 + lane] = acc[r][j];
        }
    }
}

// GATv2 per-dst online softmax + weighted aggregation. One wave per dst node.
// xr_gout: read xr row (own row only) then overwritten with the gat output.
__global__ __launch_bounds__(256) void k_gat(
    const float* __restrict__ xl, float* __restrict__ xr_gout,
    const int* __restrict__ rowptr, const int* __restrict__ esrc,
    const float* __restrict__ att, const float* __restrict__ bg, int N) {
    int wid = (blockIdx.x * blockDim.x + threadIdx.x) >> 6;
    int lane = threadIdx.x & 63;
    if (wid >= N) return;
    int n = wid;
    size_t base = (size_t)n * 512 + lane * 8;
    float xrv[8], av[8], acc[8];
#pragma unroll
    for (int j = 0; j < 8; ++j) {
        xrv[j] = xr_gout[base + j];
        av[j] = att[lane * 8 + j];
        acc[j] = 0.f;
    }
    float m = -1e30f, s = 0.f;
    int e0 = rowptr[n], e1 = rowptr[n + 1];
    for (int e = e0; e <= e1; ++e) {      // e == e1 -> self loop
        int src = (e < e1) ? esrc[e] : n;
        const float4* p = (const float4*)(xl + (size_t)src * 512 + lane * 8);
        float4 a4 = p[0], b4 = p[1];
        float xlv[8] = {a4.x, a4.y, a4.z, a4.w, b4.x, b4.y, b4.z, b4.w};
        float ps = 0.f;
#pragma unroll
        for (int j = 0; j < 8; ++j) {
            float tv = xlv[j] + xrv[j];
            tv = (tv > 0.f) ? tv : 0.2f * tv;
            ps = fmaf(tv, av[j], ps);
        }
        ps += __shfl_xor(ps, 1, 64);
        ps += __shfl_xor(ps, 2, 64);
        ps += __shfl_xor(ps, 4, 64);       // per-head score, replicated in 8-lane group
        float mnew = fmaxf(m, ps);
        float sc = __expf(m - mnew);       // 0 on first iteration
        float w = __expf(ps - mnew);
        s = s * sc + w;
#pragma unroll
        for (int j = 0; j < 8; ++j) acc[j] = acc[j] * sc + w * xlv[j];
        m = mnew;
    }
    float invs = 1.0f / s;
#pragma unroll
    for (int j = 0; j < 8; ++j)
        xr_gout[base + j] = acc[j] * invs + bg[lane * 8 + j];
}

// h1 = relu(bn(gout)) @ W_p1 + b_p1.  Block: 32 rows x 64 cols.
__global__ __launch_bounds__(256) void k_post(
    const float* __restrict__ gout, const float* __restrict__ stats,
    const float* __restrict__ g, const float* __restrict__ be,
    const float* __restrict__ Wp1, const float* __restrict__ bp1,
    float* __restrict__ h1, int N) {
    __shared__ float ytile[32][128];
    int rowbase = blockIdx.x * 32;
    int t = threadIdx.x;
    int lane = t & 63, w = t >> 6;
    float invN = 1.0f / (float)N;
    float acc[8];
#pragma unroll
    for (int r = 0; r < 8; ++r) acc[r] = 0.f;
    for (int kc = 0; kc < 4; ++kc) {
        __syncthreads();
        for (int i = t; i < 32 * 128; i += 256) {
            int r = i >> 7, kk = i & 127;
            int k = kc * 128 + kk;
            int n = rowbase + r;
            float v = 0.f;
            if (n < N) {
                float mean = stats[k] * invN;
                float var = stats[512 + k] * invN - mean * mean;
                float inv = rsqrtf(var + 1e-5f);
                float val = (gout[(size_t)n * 512 + k] - mean) * (inv * g[k]) + be[k];
                v = fmaxf(val, 0.f);
            }
            ytile[r][kk] = v;
        }
        __syncthreads();
        for (int kk4 = 0; kk4 < 32; ++kk4) {
            float bv[4];
#pragma unroll
            for (int kk = 0; kk < 4; ++kk)
                bv[kk] = Wp1[(size_t)(kc * 128 + kk4 * 4 + kk) * 64 + lane];
#pragma unroll
            for (int r = 0; r < 8; ++r) {
                float4 a4 = *(const float4*)&ytile[w * 8 + r][kk4 * 4];
                float av[4] = {a4.x, a4.y, a4.z, a4.w};
#pragma unroll
                for (int kk = 0; kk < 4; ++kk)
                    acc[r] = fmaf(av[kk], bv[kk], acc[r]);
            }
        }
    }
#pragma unroll
    for (int r = 0; r < 8; ++r) {
        int n = rowbase + w * 8 + r;
        if (n < N) h1[(size_t)n * 64 + lane] = acc[r] + bp1[lane];
    }
}

// out[n] = relu(bn(h1 row)) . W_p2 + b_p2.  One wave per node.
__global__ void k_final(const float* __restrict__ h1, const float* __restrict__ stats,
                        const float* __restrict__ g, const float* __restrict__ be,
                        const float* __restrict__ Wp2, const float* __restrict__ bp2,
                        float* __restrict__ out, int N) {
    int wid = (blockIdx.x * blockDim.x + threadIdx.x) >> 6;
    int lane = threadIdx.x & 63;
    if (wid >= N) return;
    float invN = 1.0f / (float)N;
    float mean = stats[lane] * invN;
    float var = stats[64 + lane] * invN - mean * mean;
    float inv = rsqrtf(var + 1e-5f);
    float v = h1[(size_t)wid * 64 + lane];
    v = fmaxf((v - mean) * (inv * g[lane]) + be[lane], 0.f);
    float p = v * Wp2[lane];
#pragma unroll
    for (int off = 32; off; off >>= 1) p += __shfl_xor(p, off, 64);
    if (lane == 0) out[wid] = p + bp2[0];
}

extern "C" void kernel_launch(void* const* d_in, const int* in_sizes, int n_in,
                              void* d_out, int out_size, void* d_ws, size_t ws_size,
                              hipStream_t stream) {
    const float* x      = (const float*)d_in[0];
    const int*   ei     = (const int*)d_in[1];
    const float* ea     = (const float*)d_in[2];
    const float* W_ap   = (const float*)d_in[3];
    const float* b_ap   = (const float*)d_in[4];
    const float* W_ep   = (const float*)d_in[5];
    const float* b_ep   = (const float*)d_in[6];
    const float* W_msg  = (const float*)d_in[7];
    const float* b_msg  = (const float*)d_in[8];
    const float* g_msg  = (const float*)d_in[9];
    const float* be_msg = (const float*)d_in[10];
    const float* W_l    = (const float*)d_in[11];
    const float* W_r    = (const float*)d_in[12];
    const float* att    = (const float*)d_in[13];
    const float* b_gat  = (const float*)d_in[14];
    const float* g_bn   = (const float*)d_in[15];
    const float* be_bn  = (const float*)d_in[16];
    const float* W_p1   = (const float*)d_in[17];
    const float* b_p1   = (const float*)d_in[18];
    const float* g_p    = (const float*)d_in[19];
    const float* be_p   = (const float*)d_in[20];
    const float* W_p2   = (const float*)d_in[21];
    const float* b_p2   = (const float*)d_in[22];

    int N = in_sizes[0] / 64;
    int E = in_sizes[1] / 2;

    // Workspace layout (floats). Zeroed prefix first.
    float* ws = (float*)d_ws;
    size_t off = 0;
    float* aggsum = ws + off; off += (size_t)N * 64;   // then normalized agg (in place)
    float* cnt    = ws + off; off += N;                // in-degree (float)
    int*   cursor = (int*)(ws + off); off += N;
    float* st_msg = ws + off; off += 128;
    float* st_gat = ws + off; off += 1024;
    float* st_p   = ws + off; off += 128;
    size_t zero_floats = off;
    float* atomb  = ws + off; off += (size_t)N * 64;   // later reused as h1
    float* zb     = ws + off; off += (size_t)N * 64;
    int*   rowptr = (int*)(ws + off); off += (size_t)(N + 1);
    int*   esrc   = (int*)(ws + off); off += E;
    float* xl     = ws + off; off += (size_t)N * 512;
    float* xrg    = ws + off; off += (size_t)N * 512;  // xr, overwritten by gat out
    float* h1 = atomb;

    hipMemsetAsync(d_ws, 0, zero_floats * sizeof(float), stream);

    k_rowmm64<<<CDIV(N * 64, 256), 256, 0, stream>>>(x, W_ap, b_ap, atomb, N, 64);
    k_ef<<<CDIV(E * 64, 256), 256, 0, stream>>>(ea, ei, W_ep, b_ep, aggsum, cnt, E);
    k_msg<<<CDIV(N * 64, 256), 256, 0, stream>>>(atomb, aggsum, cnt, W_msg, b_msg, zb, N);
    k_stats<<<256, 256, 0, stream>>>(zb, st_msg, N, 64);
    k_scan<<<1, 1024, 0, stream>>>(cnt, rowptr, N);
    k_fill<<<CDIV(E, 256), 256, 0, stream>>>(ei, rowptr, cursor, esrc, E);
    dim3 gx(CDIV(N, 32), 4);
    k_xlxr<<<gx, 256, 0, stream>>>(zb, aggsum, W_l, W_r, st_msg, g_msg, be_msg, xl, xrg, N);
    k_gat<<<CDIV(N * 64, 256), 256, 0, stream>>>(xl, xrg, rowptr, esrc, att, b_gat, N);
    k_stats<<<256, 256, 0, stream>>>(xrg, st_gat, N, 512);
    k_post<<<CDIV(N, 32), 256, 0, stream>>>(xrg, st_gat, g_bn, be_bn, W_p1, b_p1, h1, N);
    k_stats<<<256, 256, 0, stream>>>(h1, st_p, N, 64);
    k_final<<<CDIV(N * 64, 256), 256, 0, stream>>>(h1, st_p, g_p, be_p, W_p2, b_p2,
                                                   (float*)d_out, N);
}

// Round 2
// 770.293 us; speedup vs baseline: 1.3371x; 1.3371x over previous
//
#include <hip/hip_runtime.h>
#include <hip/hip_bf16.h>

// ---------------------------------------------------------------------------
// GATv2 model pipeline. N=50000, E=400000, HID=64, H=8.
// Round 2: MFMA bf16 GEMM for the big [N,128]@[128,1024] transform,
// parallel scan, bf16 xl for the gather-heavy GAT kernel.
// ---------------------------------------------------------------------------

#define CDIV(a, b) (((a) + (b) - 1) / (b))

using f32x4 = __attribute__((ext_vector_type(4))) float;
using s16x8 = __attribute__((ext_vector_type(8))) short;

__device__ inline unsigned short f2bf(float f) {
    union { float f; unsigned u; } v; v.f = f;
    unsigned r = v.u + 0x7fff + ((v.u >> 16) & 1);   // round-nearest-even
    return (unsigned short)(r >> 16);
}
__device__ inline float bf_lo(unsigned w) {
    union { unsigned u; float f; } v; v.u = w << 16; return v.f;
}
__device__ inline float bf_hi(unsigned w) {
    union { unsigned u; float f; } v; v.u = w & 0xffff0000u; return v.f;
}

// out[n][c] = sum_k X[n][k]*W[k][64c] + b[c], one thread per output element.
__global__ void k_rowmm64(const float* __restrict__ X, const float* __restrict__ W,
                          const float* __restrict__ b, float* __restrict__ out,
                          int N, int K) {
    int idx = blockIdx.x * blockDim.x + threadIdx.x;
    int total = N * 64;
    if (idx >= total) return;
    int n = idx >> 6, c = idx & 63;
    const float* xr = X + (size_t)n * K;
    float acc = b[c];
    for (int k = 0; k < K; ++k) acc = fmaf(xr[k], W[k * 64 + c], acc);
    out[idx] = acc;
}

// Per edge (one wave): ef = edge_attr@W_ep + b_ep; atomic scatter onto dst.
__global__ void k_ef(const float* __restrict__ EA, const int* __restrict__ ei,
                     const float* __restrict__ W, const float* __restrict__ b,
                     float* __restrict__ aggsum, float* __restrict__ cnt, int E) {
    int wid = (blockIdx.x * blockDim.x + threadIdx.x) >> 6;
    int lane = threadIdx.x & 63;
    if (wid >= E) return;
    int col = ei[E + wid];                 // edge_index[1][e] = dst
    const float* e = EA + (size_t)wid * 16;
    float acc = b[lane];
#pragma unroll
    for (int k = 0; k < 16; ++k) acc = fmaf(e[k], W[k * 64 + lane], acc);
    atomicAdd(&aggsum[(size_t)col * 64 + lane], acc);
    if (lane == 0) atomicAdd(&cnt[col], 1.0f);
}

// Per node (one wave): agg = aggsum/max(cnt,1) (in place); z = (atom+agg)@W_msg + b.
__global__ void k_msg(const float* __restrict__ atomb, float* __restrict__ agg,
                      const float* __restrict__ cnt, const float* __restrict__ Wm,
                      const float* __restrict__ bm, float* __restrict__ z, int N) {
    int wid = (blockIdx.x * blockDim.x + threadIdx.x) >> 6;
    int lane = threadIdx.x & 63;
    if (wid >= N) return;
    size_t base = (size_t)wid * 64;
    float inv = 1.0f / fmaxf(cnt[wid], 1.0f);
    float a = agg[base + lane] * inv;
    agg[base + lane] = a;
    float tv = atomb[base + lane] + a;
    float acc = bm[lane];
    for (int k = 0; k < 64; ++k) {
        float tk = __shfl(tv, k, 64);
        acc = fmaf(tk, Wm[k * 64 + lane], acc);
    }
    z[base + lane] = acc;
}

// Per-channel sum & sumsq over rows. sums[0..C)=sum, sums[C..2C)=sumsq.
__global__ void k_stats(const float* __restrict__ X, float* __restrict__ sums,
                        int N, int C) {
    int t = blockIdx.x * blockDim.x + threadIdx.x;
    int c = t % C;
    int slice = t / C;
    int nslices = (gridDim.x * blockDim.x) / C;
    float ls = 0.f, lq = 0.f;
    for (int n = slice; n < N; n += nslices) {
        float v = X[(size_t)n * C + c];
        ls += v; lq += v * v;
    }
    atomicAdd(&sums[c], ls);
    atomicAdd(&sums[C + c], lq);
}

// ---- parallel exclusive scan of cnt -> rowptr (3 kernels) ----
__global__ void k_bsum(const float* __restrict__ cnt, int* __restrict__ bsum, int N) {
    int b = blockIdx.x, t = threadIdx.x;
    int base = b * 1024 + t * 4;
    int s = 0;
#pragma unroll
    for (int j = 0; j < 4; ++j) { int i = base + j; if (i < N) s += (int)cnt[i]; }
    for (int off = 32; off; off >>= 1) s += __shfl_xor(s, off, 64);
    __shared__ int wsum[4];
    if ((t & 63) == 0) wsum[t >> 6] = s;
    __syncthreads();
    if (t == 0) bsum[b] = wsum[0] + wsum[1] + wsum[2] + wsum[3];
}
__global__ void k_boff(const int* __restrict__ bsum, int* __restrict__ boff, int nb) {
    int t = threadIdx.x;
    if (t < nb) { int s = 0; for (int j = 0; j < t; ++j) s += bsum[j]; boff[t] = s; }
}
__global__ void k_scan2(const float* __restrict__ cnt, const int* __restrict__ boff,
                        int* __restrict__ rowptr, int N) {
    int b = blockIdx.x, t = threadIdx.x;
    int base = b * 1024 + t * 4;
    int v[4]; int s = 0;
#pragma unroll
    for (int j = 0; j < 4; ++j) { int i = base + j; v[j] = (i < N) ? (int)cnt[i] : 0; s += v[j]; }
    __shared__ int ls[256];
    ls[t] = s; __syncthreads();
    for (int off = 1; off < 256; off <<= 1) {
        int tv = (t >= (int)off) ? ls[t - off] : 0;
        __syncthreads(); ls[t] += tv; __syncthreads();
    }
    int run = ls[t] - s + boff[b];
#pragma unroll
    for (int j = 0; j < 4; ++j) { run += v[j]; int i = base + j; if (i < N) rowptr[i + 1] = run; }
    if (b == 0 && t == 0) rowptr[0] = 0;
}

// Scatter edge sources into CSR order (order within a segment is arbitrary).
__global__ void k_fill(const int* __restrict__ ei, const int* __restrict__ rowptr,
                       int* __restrict__ cursor, int* __restrict__ esrc, int E) {
    int e = blockIdx.x * blockDim.x + threadIdx.x;
    if (e >= E) return;
    int dst = ei[E + e];
    int pos = rowptr[dst] + atomicAdd(&cursor[dst], 1);
    esrc[pos] = ei[e];
}

// Wt[c][k] = bf16(c<512 ? W_l[k][c] : W_r[k][c-512]); [1024][128] bf16.
__global__ void k_prep_w(const float* __restrict__ Wl, const float* __restrict__ Wr,
                         unsigned short* __restrict__ Wt) {
    int idx = blockIdx.x * blockDim.x + threadIdx.x;
    if (idx >= 1024 * 128) return;
    int c = idx >> 7, k = idx & 127;
    float v = (c < 512) ? Wl[(size_t)k * 512 + c] : Wr[(size_t)k * 512 + (c - 512)];
    Wt[idx] = f2bf(v);
}

// comb[n][k] = bf16(k<64 ? relu(bn(z)) : agg), [N][128] bf16.
__global__ void k_comb(const float* __restrict__ z, const float* __restrict__ agg,
                       const float* __restrict__ stats, const float* __restrict__ g,
                       const float* __restrict__ be, unsigned short* __restrict__ comb,
                       int N) {
    int idx = blockIdx.x * blockDim.x + threadIdx.x;
    if (idx >= N * 128) return;
    int n = idx >> 7, k = idx & 127;
    float v;
    if (k < 64) {
        float invN = 1.0f / (float)N;
        float mean = stats[k] * invN;
        float var = stats[64 + k] * invN - mean * mean;
        float inv = rsqrtf(var + 1e-5f);
        v = fmaxf((z[(size_t)n * 64 + k] - mean) * (inv * g[k]) + be[k], 0.f);
    } else {
        v = agg[(size_t)n * 64 + (k - 64)];
    }
    comb[idx] = f2bf(v);
}

// MFMA GEMM: out[N][1024] = comb[N][128] @ Wt^T. Block = 64 rows x 64 cols,
// 4 waves (one 16-row strip each). y<8 -> xl (bf16), y>=8 -> xr (f32).
__global__ __launch_bounds__(256) void k_xlxr_mfma(
    const unsigned short* __restrict__ comb, const unsigned short* __restrict__ Wt,
    unsigned short* __restrict__ xl, float* __restrict__ xr, int N) {
    __shared__ unsigned short a_lds[64 * 128];
    __shared__ unsigned short b_lds[64 * 128];
    int t = threadIdx.x;
    int row0 = blockIdx.x * 64;
    int c0 = blockIdx.y * 64;
    // stage: 1024 16B chunks each, XOR-swizzled so ds_read_b128 is conflict-free
    for (int i = t; i < 1024; i += 256) {
        int row = i >> 4, seg = i & 15;
        int dsts = (row * 256 + ((seg * 16) ^ ((row & 7) << 4))) >> 1;  // shorts
        int gr = row0 + row;
        if (gr < N) {
            *(s16x8*)(a_lds + dsts) = *(const s16x8*)(comb + (size_t)gr * 128 + seg * 8);
        } else {
            s16x8 zz = (s16x8)0; *(s16x8*)(a_lds + dsts) = zz;
        }
    }
    for (int i = t; i < 1024; i += 256) {
        int row = i >> 4, seg = i & 15;
        int dsts = (row * 256 + ((seg * 16) ^ ((row & 7) << 4))) >> 1;
        *(s16x8*)(b_lds + dsts) = *(const s16x8*)(Wt + (size_t)(c0 + row) * 128 + seg * 8);
    }
    __syncthreads();
    int w = t >> 6, l = t & 63;
    int hi = l >> 4, lo = l & 15;
    s16x8 a[4], b[4][4];
    int ar = w * 16 + lo;
#pragma unroll
    for (int kk = 0; kk < 4; ++kk) {
        int byte = (kk * 64 + hi * 16) ^ ((ar & 7) << 4);
        a[kk] = *(const s16x8*)(a_lds + ((ar * 256 + byte) >> 1));
    }
#pragma unroll
    for (int cf = 0; cf < 4; ++cf) {
        int br = cf * 16 + lo;
#pragma unroll
        for (int kk = 0; kk < 4; ++kk) {
            int byte = (kk * 64 + hi * 16) ^ ((br & 7) << 4);
            b[cf][kk] = *(const s16x8*)(b_lds + ((br * 256 + byte) >> 1));
        }
    }
    f32x4 acc[4];
#pragma unroll
    for (int cf = 0; cf < 4; ++cf) acc[cf] = (f32x4){0.f, 0.f, 0.f, 0.f};
#pragma unroll
    for (int kk = 0; kk < 4; ++kk)
#pragma unroll
        for (int cf = 0; cf < 4; ++cf)
            acc[cf] = __builtin_amdgcn_mfma_f32_16x16x32_bf16(a[kk], b[cf][kk], acc[cf], 0, 0, 0);
    bool isl = blockIdx.y < 8;
#pragma unroll
    for (int cf = 0; cf < 4; ++cf) {
        int colg = c0 + cf * 16 + lo;
#pragma unroll
        for (int r = 0; r < 4; ++r) {
            int rowg = row0 + w * 16 + hi * 4 + r;
            if (rowg < N) {
                if (isl) xl[(size_t)rowg * 512 + colg] = f2bf(acc[cf][r]);
                else     xr[(size_t)rowg * 512 + (colg - 512)] = acc[cf][r];
            }
        }
    }
}

// GATv2 per-dst online softmax + weighted aggregation. One wave per dst node.
// xl is bf16; xr_gout (f32) is read (own row) then overwritten with output.
__global__ __launch_bounds__(256) void k_gat(
    const unsigned short* __restrict__ xl, float* __restrict__ xr_gout,
    const int* __restrict__ rowptr, const int* __restrict__ esrc,
    const float* __restrict__ att, const float* __restrict__ bg, int N) {
    int wid = (blockIdx.x * blockDim.x + threadIdx.x) >> 6;
    int lane = threadIdx.x & 63;
    if (wid >= N) return;
    int n = wid;
    size_t base = (size_t)n * 512 + lane * 8;
    float xrv[8], av[8], acc[8];
#pragma unroll
    for (int j = 0; j < 8; ++j) {
        xrv[j] = xr_gout[base + j];
        av[j] = att[lane * 8 + j];
        acc[j] = 0.f;
    }
    float m = -1e30f, s = 0.f;
    int e0 = rowptr[n], e1 = rowptr[n + 1];
    for (int e = e0; e <= e1; ++e) {      // e == e1 -> self loop
        int src = (e < e1) ? esrc[e] : n;
        uint4 u = *(const uint4*)(xl + (size_t)src * 512 + lane * 8);
        float xlv[8] = {bf_lo(u.x), bf_hi(u.x), bf_lo(u.y), bf_hi(u.y),
                        bf_lo(u.z), bf_hi(u.z), bf_lo(u.w), bf_hi(u.w)};
        float ps = 0.f;
#pragma unroll
        for (int j = 0; j < 8; ++j) {
            float tv = xlv[j] + xrv[j];
            tv = (tv > 0.f) ? tv : 0.2f * tv;
            ps = fmaf(tv, av[j], ps);
        }
        ps += __shfl_xor(ps, 1, 64);
        ps += __shfl_xor(ps, 2, 64);
        ps += __shfl_xor(ps, 4, 64);       // per-head score, replicated in 8-lane group
        float mnew = fmaxf(m, ps);
        float sc = __expf(m - mnew);
        float w = __expf(ps - mnew);
        s = s * sc + w;
#pragma unroll
        for (int j = 0; j < 8; ++j) acc[j] = acc[j] * sc + w * xlv[j];
        m = mnew;
    }
    float invs = 1.0f / s;
#pragma unroll
    for (int j = 0; j < 8; ++j)
        xr_gout[base + j] = acc[j] * invs + bg[lane * 8 + j];
}

// h1 = relu(bn(gout)) @ W_p1 + b_p1.  Block: 32 rows x 64 cols.
__global__ __launch_bounds__(256) void k_post(
    const float* __restrict__ gout, const float* __restrict__ stats,
    const float* __restrict__ g, const float* __restrict__ be,
    const float* __restrict__ Wp1, const float* __restrict__ bp1,
    float* __restrict__ h1, int N) {
    __shared__ float ytile[32][128];
    int rowbase = blockIdx.x * 32;
    int t = threadIdx.x;
    int lane = t & 63, w = t >> 6;
    float invN = 1.0f / (float)N;
    float acc[8];
#pragma unroll
    for (int r = 0; r < 8; ++r) acc[r] = 0.f;
    for (int kc = 0; kc < 4; ++kc) {
        __syncthreads();
        for (int i = t; i < 32 * 128; i += 256) {
            int r = i >> 7, kk = i & 127;
            int k = kc * 128 + kk;
            int n = rowbase + r;
            float v = 0.f;
            if (n < N) {
                float mean = stats[k] * invN;
                float var = stats[512 + k] * invN - mean * mean;
                float inv = rsqrtf(var + 1e-5f);
                float val = (gout[(size_t)n * 512 + k] - mean) * (inv * g[k]) + be[k];
                v = fmaxf(val, 0.f);
            }
            ytile[r][kk] = v;
        }
        __syncthreads();
        for (int kk4 = 0; kk4 < 32; ++kk4) {
            float bv[4];
#pragma unroll
            for (int kk = 0; kk < 4; ++kk)
                bv[kk] = Wp1[(size_t)(kc * 128 + kk4 * 4 + kk) * 64 + lane];
#pragma unroll
            for (int r = 0; r < 8; ++r) {
                float4 a4 = *(const float4*)&ytile[w * 8 + r][kk4 * 4];
                float av[4] = {a4.x, a4.y, a4.z, a4.w};
#pragma unroll
                for (int kk = 0; kk < 4; ++kk)
                    acc[r] = fmaf(av[kk], bv[kk], acc[r]);
            }
        }
    }
#pragma unroll
    for (int r = 0; r < 8; ++r) {
        int n = rowbase + w * 8 + r;
        if (n < N) h1[(size_t)n * 64 + lane] = acc[r] + bp1[lane];
    }
}

// out[n] = relu(bn(h1 row)) . W_p2 + b_p2.  One wave per node.
__global__ void k_final(const float* __restrict__ h1, const float* __restrict__ stats,
                        const float* __restrict__ g, const float* __restrict__ be,
                        const float* __restrict__ Wp2, const float* __restrict__ bp2,
                        float* __restrict__ out, int N) {
    int wid = (blockIdx.x * blockDim.x + threadIdx.x) >> 6;
    int lane = threadIdx.x & 63;
    if (wid >= N) return;
    float invN = 1.0f / (float)N;
    float mean = stats[lane] * invN;
    float var = stats[64 + lane] * invN - mean * mean;
    float inv = rsqrtf(var + 1e-5f);
    float v = h1[(size_t)wid * 64 + lane];
    v = fmaxf((v - mean) * (inv * g[lane]) + be[lane], 0.f);
    float p = v * Wp2[lane];
#pragma unroll
    for (int off = 32; off; off >>= 1) p += __shfl_xor(p, off, 64);
    if (lane == 0) out[wid] = p + bp2[0];
}

extern "C" void kernel_launch(void* const* d_in, const int* in_sizes, int n_in,
                              void* d_out, int out_size, void* d_ws, size_t ws_size,
                              hipStream_t stream) {
    const float* x      = (const float*)d_in[0];
    const int*   ei     = (const int*)d_in[1];
    const float* ea     = (const float*)d_in[2];
    const float* W_ap   = (const float*)d_in[3];
    const float* b_ap   = (const float*)d_in[4];
    const float* W_ep   = (const float*)d_in[5];
    const float* b_ep   = (const float*)d_in[6];
    const float* W_msg  = (const float*)d_in[7];
    const float* b_msg  = (const float*)d_in[8];
    const float* g_msg  = (const float*)d_in[9];
    const float* be_msg = (const float*)d_in[10];
    const float* W_l    = (const float*)d_in[11];
    const float* W_r    = (const float*)d_in[12];
    const float* att    = (const float*)d_in[13];
    const float* b_gat  = (const float*)d_in[14];
    const float* g_bn   = (const float*)d_in[15];
    const float* be_bn  = (const float*)d_in[16];
    const float* W_p1   = (const float*)d_in[17];
    const float* b_p1   = (const float*)d_in[18];
    const float* g_p    = (const float*)d_in[19];
    const float* be_p   = (const float*)d_in[20];
    const float* W_p2   = (const float*)d_in[21];
    const float* b_p2   = (const float*)d_in[22];

    int N = in_sizes[0] / 64;
    int E = in_sizes[1] / 2;
    int nb = CDIV(N, 1024);

    // Workspace layout (floats). Zeroed prefix first.
    float* ws = (float*)d_ws;
    size_t off = 0;
    float* aggsum = ws + off; off += (size_t)N * 64;   // then normalized agg (in place)
    float* cnt    = ws + off; off += N;                // in-degree (float)
    int*   cursor = (int*)(ws + off); off += N;
    float* st_msg = ws + off; off += 128;
    float* st_gat = ws + off; off += 1024;
    float* st_p   = ws + off; off += 128;
    size_t zero_floats = off;
    float* atomb  = ws + off; off += (size_t)N * 64;   // later reused as h1
    float* zb     = ws + off; off += (size_t)N * 64;
    int*   rowptr = (int*)(ws + off); off += (size_t)(N + 1); off = (off + 3) & ~(size_t)3;
    int*   esrc   = (int*)(ws + off); off += E;
    int*   bsum   = (int*)(ws + off); off += 64;
    int*   boff   = (int*)(ws + off); off += 64;
    unsigned short* comb = (unsigned short*)(ws + off); off += (size_t)N * 64;   // N*128 bf16
    unsigned short* Wt   = (unsigned short*)(ws + off); off += 65536;            // 1024*128 bf16
    unsigned short* xl   = (unsigned short*)(ws + off); off += (size_t)N * 256;  // N*512 bf16
    float* xrg    = ws + off; off += (size_t)N * 512;  // xr f32, overwritten by gat out
    float* h1 = atomb;

    hipMemsetAsync(d_ws, 0, zero_floats * sizeof(float), stream);

    k_rowmm64<<<CDIV(N * 64, 256), 256, 0, stream>>>(x, W_ap, b_ap, atomb, N, 64);
    k_prep_w<<<CDIV(1024 * 128, 256), 256, 0, stream>>>(W_l, W_r, Wt);
    k_ef<<<CDIV(E * 64, 256), 256, 0, stream>>>(ea, ei, W_ep, b_ep, aggsum, cnt, E);
    k_msg<<<CDIV(N * 64, 256), 256, 0, stream>>>(atomb, aggsum, cnt, W_msg, b_msg, zb, N);
    k_stats<<<256, 256, 0, stream>>>(zb, st_msg, N, 64);
    k_comb<<<CDIV(N * 128, 256), 256, 0, stream>>>(zb, aggsum, st_msg, g_msg, be_msg, comb, N);
    k_bsum<<<nb, 256, 0, stream>>>(cnt, bsum, N);
    k_boff<<<1, 64, 0, stream>>>(bsum, boff, nb);
    k_scan2<<<nb, 256, 0, stream>>>(cnt, boff, rowptr, N);
    k_fill<<<CDIV(E, 256), 256, 0, stream>>>(ei, rowptr, cursor, esrc, E);
    dim3 gx(CDIV(N, 64), 16);
    k_xlxr_mfma<<<gx, 256, 0, stream>>>(comb, Wt, xl, xrg, N);
    k_gat<<<CDIV(N * 64, 256), 256, 0, stream>>>(xl, xrg, rowptr, esrc, att, b_gat, N);
    k_stats<<<256, 256, 0, stream>>>(xrg, st_gat, N, 512);
    k_post<<<CDIV(N, 32), 256, 0, stream>>>(xrg, st_gat, g_bn, be_bn, W_p1, b_p1, h1, N);
    k_stats<<<256, 256, 0, stream>>>(h1, st_p, N, 64);
    k_final<<<CDIV(N * 64, 256), 256, 0, stream>>>(h1, st_p, g_p, be_p, W_p2, b_p2,
                                                   (float*)d_out, N);
}

// Round 3
// 628.568 us; speedup vs baseline: 1.6385x; 1.2255x over previous
//
#include <hip/hip_runtime.h>
#include <hip/hip_bf16.h>

// ---------------------------------------------------------------------------
// GATv2 model pipeline. N=50000, E=400000, HID=64, H=8.
// Round 3: scatter only 16-wide edge_attr (linearity of scatter_mean),
// fold atom/msg GEMMs into one MFMA GEMM via W_ap@W_msg, 64x256 GEMM2 tiles.
// ---------------------------------------------------------------------------

#define CDIV(a, b) (((a) + (b) - 1) / (b))

using f32x4 = __attribute__((ext_vector_type(4))) float;
using s16x8 = __attribute__((ext_vector_type(8))) short;

__device__ inline unsigned short f2bf(float f) {
    union { float f; unsigned u; } v; v.f = f;
    unsigned r = v.u + 0x7fff + ((v.u >> 16) & 1);   // round-nearest-even
    return (unsigned short)(r >> 16);
}
__device__ inline float bf_lo(unsigned w) {
    union { unsigned u; float f; } v; v.u = w << 16; return v.f;
}
__device__ inline float bf_hi(unsigned w) {
    union { unsigned u; float f; } v; v.u = w & 0xffff0000u; return v.f;
}

// Scatter raw edge_attr (16 ch) onto dst nodes + integer degree count.
__global__ void k_scatter16(const float* __restrict__ EA, const int* __restrict__ ei,
                            float* __restrict__ agg16, int* __restrict__ cntI, int E) {
    int t = blockIdx.x * blockDim.x + threadIdx.x;
    int e = t >> 4, ch = t & 15;
    if (e >= E) return;
    int dst = ei[E + e];
    atomicAdd(&agg16[(size_t)dst * 16 + ch], EA[(size_t)e * 16 + ch]);
    if (ch == 0) atomicAdd(&cntI[dst], 1);
}

// Wzt[c][0:64] = (W_ap@W_msg)[:,c], Wzt[c][64:128] = W_msg[:,c]; bc = b_ap@W_msg+b_msg.
__global__ void k_wc(const float* __restrict__ Wap, const float* __restrict__ Wmsg,
                     const float* __restrict__ bap, const float* __restrict__ bmsg,
                     unsigned short* __restrict__ Wzt, float* __restrict__ bc) {
    int t = threadIdx.x;
    for (int e = t; e < 4096; e += 256) {
        int i = e >> 6, c = e & 63;
        float s = 0.f;
        for (int j = 0; j < 64; ++j) s += Wap[i * 64 + j] * Wmsg[j * 64 + c];
        Wzt[c * 128 + i] = f2bf(s);
    }
    for (int e = t; e < 4096; e += 256) {
        int k = e >> 6, c = e & 63;
        Wzt[c * 128 + 64 + k] = f2bf(Wmsg[k * 64 + c]);
    }
    if (t < 64) {
        float s = bmsg[t];
        for (int j = 0; j < 64; ++j) s += bap[j] * Wmsg[j * 64 + t];
        bc[t] = s;
    }
}

// combin[n][0:64] = bf16(x[n])
__global__ void k_xbf(const float* __restrict__ x, unsigned short* __restrict__ combin, int N) {
    int idx = blockIdx.x * blockDim.x + threadIdx.x;
    if (idx >= N * 64) return;
    int n = idx >> 6, k = idx & 63;
    combin[(size_t)n * 128 + k] = f2bf(x[idx]);
}

// combin[n][64:128] = bf16(agg[n]) where agg = cnt>0 ? mean(ea)@W_ep + b_ep : 0.
__global__ void k_aggfin(const float* __restrict__ agg16, const int* __restrict__ cntI,
                         const float* __restrict__ Wep, const float* __restrict__ bep,
                         unsigned short* __restrict__ combin, int N) {
    int wid = (blockIdx.x * blockDim.x + threadIdx.x) >> 6;
    int lane = threadIdx.x & 63;
    if (wid >= N) return;
    int c = cntI[wid];
    float mval = (lane < 16 && c > 0) ? agg16[(size_t)wid * 16 + lane] / (float)c : 0.f;
    float acc = bep[lane];
#pragma unroll
    for (int j = 0; j < 16; ++j) {
        float mj = __shfl(mval, j, 64);
        acc = fmaf(mj, Wep[j * 64 + lane], acc);
    }
    if (c == 0) acc = 0.f;
    combin[(size_t)wid * 128 + 64 + lane] = f2bf(acc);
}

// MFMA GEMM1: z[N][64] = combin[N][128] @ Wzt^T + bc. Block 64 rows, 4 waves.
__global__ __launch_bounds__(256) void k_z(
    const unsigned short* __restrict__ combin, const unsigned short* __restrict__ Wzt,
    const float* __restrict__ bc, float* __restrict__ z, int N) {
    __shared__ unsigned short a_lds[64 * 128];
    __shared__ unsigned short b_lds[64 * 128];
    int t = threadIdx.x;
    int row0 = blockIdx.x * 64;
    for (int i = t; i < 1024; i += 256) {
        int row = i >> 4, seg = i & 15;
        int dsts = (row * 256 + ((seg * 16) ^ ((row & 7) << 4))) >> 1;
        int gr = row0 + row;
        s16x8 v = (s16x8)0;
        if (gr < N) v = *(const s16x8*)(combin + (size_t)gr * 128 + seg * 8);
        *(s16x8*)(a_lds + dsts) = v;
        *(s16x8*)(b_lds + dsts) = *(const s16x8*)(Wzt + (size_t)row * 128 + seg * 8);
    }
    __syncthreads();
    int w = t >> 6, l = t & 63, hi = l >> 4, lo = l & 15;
    int ar = w * 16 + lo;
    s16x8 a[4];
#pragma unroll
    for (int kk = 0; kk < 4; ++kk) {
        int byte = (kk * 64 + hi * 16) ^ ((ar & 7) << 4);
        a[kk] = *(const s16x8*)(a_lds + ((ar * 256 + byte) >> 1));
    }
#pragma unroll
    for (int cf = 0; cf < 4; ++cf) {
        int br = cf * 16 + lo;
        f32x4 acc = (f32x4){0.f, 0.f, 0.f, 0.f};
#pragma unroll
        for (int kk = 0; kk < 4; ++kk) {
            int byte = (kk * 64 + hi * 16) ^ ((br & 7) << 4);
            s16x8 b = *(const s16x8*)(b_lds + ((br * 256 + byte) >> 1));
            acc = __builtin_amdgcn_mfma_f32_16x16x32_bf16(a[kk], b, acc, 0, 0, 0);
        }
        int colg = cf * 16 + lo;
#pragma unroll
        for (int r = 0; r < 4; ++r) {
            int rowg = row0 + w * 16 + hi * 4 + r;
            if (rowg < N) z[(size_t)rowg * 64 + colg] = acc[r] + bc[colg];
        }
    }
}

// Per-channel sum & sumsq over rows. sums[0..C)=sum, sums[C..2C)=sumsq.
__global__ void k_stats(const float* __restrict__ X, float* __restrict__ sums,
                        int N, int C) {
    int t = blockIdx.x * blockDim.x + threadIdx.x;
    int c = t % C;
    int slice = t / C;
    int nslices = (gridDim.x * blockDim.x) / C;
    float ls = 0.f, lq = 0.f;
    for (int n = slice; n < N; n += nslices) {
        float v = X[(size_t)n * C + c];
        ls += v; lq += v * v;
    }
    atomicAdd(&sums[c], ls);
    atomicAdd(&sums[C + c], lq);
}

// combin[n][0:64] = bf16(relu(bn(z[n])))  (in place; x part no longer needed)
__global__ void k_comb2(const float* __restrict__ z, const float* __restrict__ stats,
                        const float* __restrict__ g, const float* __restrict__ be,
                        unsigned short* __restrict__ combin, int N) {
    int idx = blockIdx.x * blockDim.x + threadIdx.x;
    if (idx >= N * 64) return;
    int n = idx >> 6, k = idx & 63;
    float invN = 1.0f / (float)N;
    float mean = stats[k] * invN;
    float var = stats[64 + k] * invN - mean * mean;
    float inv = rsqrtf(var + 1e-5f);
    float v = fmaxf((z[idx] - mean) * (inv * g[k]) + be[k], 0.f);
    combin[(size_t)n * 128 + k] = f2bf(v);
}

// ---- parallel exclusive scan of cntI -> rowptr (3 kernels) ----
__global__ void k_bsum(const int* __restrict__ cntI, int* __restrict__ bsum, int N) {
    int b = blockIdx.x, t = threadIdx.x;
    int base = b * 1024 + t * 4;
    int s = 0;
#pragma unroll
    for (int j = 0; j < 4; ++j) { int i = base + j; if (i < N) s += cntI[i]; }
    for (int off = 32; off; off >>= 1) s += __shfl_xor(s, off, 64);
    __shared__ int wsum[4];
    if ((t & 63) == 0) wsum[t >> 6] = s;
    __syncthreads();
    if (t == 0) bsum[b] = wsum[0] + wsum[1] + wsum[2] + wsum[3];
}
__global__ void k_boff(const int* __restrict__ bsum, int* __restrict__ boff, int nb) {
    int t = threadIdx.x;
    if (t < nb) { int s = 0; for (int j = 0; j < t; ++j) s += bsum[j]; boff[t] = s; }
}
__global__ void k_scan2(const int* __restrict__ cntI, const int* __restrict__ boff,
                        int* __restrict__ rowptr, int N) {
    int b = blockIdx.x, t = threadIdx.x;
    int base = b * 1024 + t * 4;
    int v[4]; int s = 0;
#pragma unroll
    for (int j = 0; j < 4; ++j) { int i = base + j; v[j] = (i < N) ? cntI[i] : 0; s += v[j]; }
    __shared__ int ls[256];
    ls[t] = s; __syncthreads();
    for (int off = 1; off < 256; off <<= 1) {
        int tv = (t >= (int)off) ? ls[t - off] : 0;
        __syncthreads(); ls[t] += tv; __syncthreads();
    }
    int run = ls[t] - s + boff[b];
#pragma unroll
    for (int j = 0; j < 4; ++j) { run += v[j]; int i = base + j; if (i < N) rowptr[i + 1] = run; }
    if (b == 0 && t == 0) rowptr[0] = 0;
}

// Scatter edge sources into CSR order (order within a segment is arbitrary).
__global__ void k_fill(const int* __restrict__ ei, const int* __restrict__ rowptr,
                       int* __restrict__ cursor, int* __restrict__ esrc, int E) {
    int e = blockIdx.x * blockDim.x + threadIdx.x;
    if (e >= E) return;
    int dst = ei[E + e];
    int pos = rowptr[dst] + atomicAdd(&cursor[dst], 1);
    esrc[pos] = ei[e];
}

// Wt[c][k] = bf16(c<512 ? W_l[k][c] : W_r[k][c-512]); [1024][128] bf16.
__global__ void k_prep_w(const float* __restrict__ Wl, const float* __restrict__ Wr,
                         unsigned short* __restrict__ Wt) {
    int idx = blockIdx.x * blockDim.x + threadIdx.x;
    if (idx >= 1024 * 128) return;
    int c = idx >> 7, k = idx & 127;
    float v = (c < 512) ? Wl[(size_t)k * 512 + c] : Wr[(size_t)k * 512 + (c - 512)];
    Wt[idx] = f2bf(v);
}

// MFMA GEMM2: out[N][1024] = combin[N][128] @ Wt^T. Block 64 rows x 256 cols.
// blockIdx.y<2 -> xl (bf16), else xr (f32).
__global__ __launch_bounds__(256) void k_xlxr2(
    const unsigned short* __restrict__ combin, const unsigned short* __restrict__ Wt,
    unsigned short* __restrict__ xl, float* __restrict__ xr, int N) {
    __shared__ unsigned short a_lds[64 * 128];
    __shared__ unsigned short b_lds[256 * 128];
    int t = threadIdx.x;
    int row0 = blockIdx.x * 64;
    int c0 = blockIdx.y * 256;
    for (int i = t; i < 1024; i += 256) {
        int row = i >> 4, seg = i & 15;
        int dsts = (row * 256 + ((seg * 16) ^ ((row & 7) << 4))) >> 1;
        int gr = row0 + row;
        s16x8 v = (s16x8)0;
        if (gr < N) v = *(const s16x8*)(combin + (size_t)gr * 128 + seg * 8);
        *(s16x8*)(a_lds + dsts) = v;
    }
    for (int i = t; i < 4096; i += 256) {
        int row = i >> 4, seg = i & 15;
        int dsts = (row * 256 + ((seg * 16) ^ ((row & 7) << 4))) >> 1;
        *(s16x8*)(b_lds + dsts) = *(const s16x8*)(Wt + (size_t)(c0 + row) * 128 + seg * 8);
    }
    __syncthreads();
    int w = t >> 6, l = t & 63, hi = l >> 4, lo = l & 15;
    int ar = w * 16 + lo;
    s16x8 a[4];
#pragma unroll
    for (int kk = 0; kk < 4; ++kk) {
        int byte = (kk * 64 + hi * 16) ^ ((ar & 7) << 4);
        a[kk] = *(const s16x8*)(a_lds + ((ar * 256 + byte) >> 1));
    }
    bool isl = c0 < 512;
#pragma unroll
    for (int cf = 0; cf < 16; ++cf) {
        int br = cf * 16 + lo;
        f32x4 acc = (f32x4){0.f, 0.f, 0.f, 0.f};
#pragma unroll
        for (int kk = 0; kk < 4; ++kk) {
            int byte = (kk * 64 + hi * 16) ^ ((br & 7) << 4);
            s16x8 b = *(const s16x8*)(b_lds + ((br * 256 + byte) >> 1));
            acc = __builtin_amdgcn_mfma_f32_16x16x32_bf16(a[kk], b, acc, 0, 0, 0);
        }
        int colg = c0 + cf * 16 + lo;
#pragma unroll
        for (int r = 0; r < 4; ++r) {
            int rowg = row0 + w * 16 + hi * 4 + r;
            if (rowg < N) {
                if (isl) xl[(size_t)rowg * 512 + colg] = f2bf(acc[r]);
                else     xr[(size_t)rowg * 512 + (colg - 512)] = acc[r];
            }
        }
    }
}

// GATv2 per-dst online softmax + weighted aggregation. One wave per dst node.
__global__ __launch_bounds__(256) void k_gat(
    const unsigned short* __restrict__ xl, float* __restrict__ xr_gout,
    const int* __restrict__ rowptr, const int* __restrict__ esrc,
    const float* __restrict__ att, const float* __restrict__ bg, int N) {
    int wid = (blockIdx.x * blockDim.x + threadIdx.x) >> 6;
    int lane = threadIdx.x & 63;
    if (wid >= N) return;
    int n = wid;
    size_t base = (size_t)n * 512 + lane * 8;
    float xrv[8], av[8], acc[8];
#pragma unroll
    for (int j = 0; j < 8; ++j) {
        xrv[j] = xr_gout[base + j];
        av[j] = att[lane * 8 + j];
        acc[j] = 0.f;
    }
    float m = -1e30f, s = 0.f;
    int e0 = rowptr[n], e1 = rowptr[n + 1];
    for (int e = e0; e <= e1; ++e) {      // e == e1 -> self loop
        int src = (e < e1) ? esrc[e] : n;
        uint4 u = *(const uint4*)(xl + (size_t)src * 512 + lane * 8);
        float xlv[8] = {bf_lo(u.x), bf_hi(u.x), bf_lo(u.y), bf_hi(u.y),
                        bf_lo(u.z), bf_hi(u.z), bf_lo(u.w), bf_hi(u.w)};
        float ps = 0.f;
#pragma unroll
        for (int j = 0; j < 8; ++j) {
            float tv = xlv[j] + xrv[j];
            tv = (tv > 0.f) ? tv : 0.2f * tv;
            ps = fmaf(tv, av[j], ps);
        }
        ps += __shfl_xor(ps, 1, 64);
        ps += __shfl_xor(ps, 2, 64);
        ps += __shfl_xor(ps, 4, 64);       // per-head score, replicated in 8-lane group
        float mnew = fmaxf(m, ps);
        float sc = __expf(m - mnew);
        float w = __expf(ps - mnew);
        s = s * sc + w;
#pragma unroll
        for (int j = 0; j < 8; ++j) acc[j] = acc[j] * sc + w * xlv[j];
        m = mnew;
    }
    float invs = 1.0f / s;
#pragma unroll
    for (int j = 0; j < 8; ++j)
        xr_gout[base + j] = acc[j] * invs + bg[lane * 8 + j];
}

// h1 = relu(bn(gout)) @ W_p1 + b_p1.  Block: 32 rows x 64 cols.
__global__ __launch_bounds__(256) void k_post(
    const float* __restrict__ gout, const float* __restrict__ stats,
    const float* __restrict__ g, const float* __restrict__ be,
    const float* __restrict__ Wp1, const float* __restrict__ bp1,
    float* __restrict__ h1, int N) {
    __shared__ float ytile[32][128];
    int rowbase = blockIdx.x * 32;
    int t = threadIdx.x;
    int lane = t & 63, w = t >> 6;
    float invN = 1.0f / (float)N;
    float acc[8];
#pragma unroll
    for (int r = 0; r < 8; ++r) acc[r] = 0.f;
    for (int kc = 0; kc < 4; ++kc) {
        __syncthreads();
        for (int i = t; i < 32 * 128; i += 256) {
            int r = i >> 7, kk = i & 127;
            int k = kc * 128 + kk;
            int n = rowbase + r;
            float v = 0.f;
            if (n < N) {
                float mean = stats[k] * invN;
                float var = stats[512 + k] * invN - mean * mean;
                float inv = rsqrtf(var + 1e-5f);
                float val = (gout[(size_t)n * 512 + k] - mean) * (inv * g[k]) + be[k];
                v = fmaxf(val, 0.f);
            }
            ytile[r][kk] = v;
        }
        __syncthreads();
        for (int kk4 = 0; kk4 < 32; ++kk4) {
            float bv[4];
#pragma unroll
            for (int kk = 0; kk < 4; ++kk)
                bv[kk] = Wp1[(size_t)(kc * 128 + kk4 * 4 + kk) * 64 + lane];
#pragma unroll
            for (int r = 0; r < 8; ++r) {
                float4 a4 = *(const float4*)&ytile[w * 8 + r][kk4 * 4];
                float av[4] = {a4.x, a4.y, a4.z, a4.w};
#pragma unroll
                for (int kk = 0; kk < 4; ++kk)
                    acc[r] = fmaf(av[kk], bv[kk], acc[r]);
            }
        }
    }
#pragma unroll
    for (int r = 0; r < 8; ++r) {
        int n = rowbase + w * 8 + r;
        if (n < N) h1[(size_t)n * 64 + lane] = acc[r] + bp1[lane];
    }
}

// out[n] = relu(bn(h1 row)) . W_p2 + b_p2.  One wave per node.
__global__ void k_final(const float* __restrict__ h1, const float* __restrict__ stats,
                        const float* __restrict__ g, const float* __restrict__ be,
                        const float* __restrict__ Wp2, const float* __restrict__ bp2,
                        float* __restrict__ out, int N) {
    int wid = (blockIdx.x * blockDim.x + threadIdx.x) >> 6;
    int lane = threadIdx.x & 63;
    if (wid >= N) return;
    float invN = 1.0f / (float)N;
    float mean = stats[lane] * invN;
    float var = stats[64 + lane] * invN - mean * mean;
    float inv = rsqrtf(var + 1e-5f);
    float v = h1[(size_t)wid * 64 + lane];
    v = fmaxf((v - mean) * (inv * g[lane]) + be[lane], 0.f);
    float p = v * Wp2[lane];
#pragma unroll
    for (int off = 32; off; off >>= 1) p += __shfl_xor(p, off, 64);
    if (lane == 0) out[wid] = p + bp2[0];
}

extern "C" void kernel_launch(void* const* d_in, const int* in_sizes, int n_in,
                              void* d_out, int out_size, void* d_ws, size_t ws_size,
                              hipStream_t stream) {
    const float* x      = (const float*)d_in[0];
    const int*   ei     = (const int*)d_in[1];
    const float* ea     = (const float*)d_in[2];
    const float* W_ap   = (const float*)d_in[3];
    const float* b_ap   = (const float*)d_in[4];
    const float* W_ep   = (const float*)d_in[5];
    const float* b_ep   = (const float*)d_in[6];
    const float* W_msg  = (const float*)d_in[7];
    const float* b_msg  = (const float*)d_in[8];
    const float* g_msg  = (const float*)d_in[9];
    const float* be_msg = (const float*)d_in[10];
    const float* W_l    = (const float*)d_in[11];
    const float* W_r    = (const float*)d_in[12];
    const float* att    = (const float*)d_in[13];
    const float* b_gat  = (const float*)d_in[14];
    const float* g_bn   = (const float*)d_in[15];
    const float* be_bn  = (const float*)d_in[16];
    const float* W_p1   = (const float*)d_in[17];
    const float* b_p1   = (const float*)d_in[18];
    const float* g_p    = (const float*)d_in[19];
    const float* be_p   = (const float*)d_in[20];
    const float* W_p2   = (const float*)d_in[21];
    const float* b_p2   = (const float*)d_in[22];

    int N = in_sizes[0] / 64;
    int E = in_sizes[1] / 2;
    int nb = CDIV(N, 1024);

    // Workspace layout (floats). Zeroed prefix first.
    float* ws = (float*)d_ws;
    size_t off = 0;
    float* agg16  = ws + off; off += (size_t)N * 16;
    int*   cntI   = (int*)(ws + off); off += N;
    int*   cursor = (int*)(ws + off); off += N;
    float* st_msg = ws + off; off += 128;
    float* st_gat = ws + off; off += 1024;
    float* st_p   = ws + off; off += 128;
    size_t zero_floats = off;
    unsigned short* combin = (unsigned short*)(ws + off); off += (size_t)N * 64;  // N*128 bf16
    float* zb     = ws + off; off += (size_t)N * 64;       // z, later reused as h1
    unsigned short* Wzt = (unsigned short*)(ws + off); off += 4096;               // 64*128 bf16
    float* bc     = ws + off; off += 64;
    int*   rowptr = (int*)(ws + off); off += (size_t)(N + 1); off = (off + 3) & ~(size_t)3;
    int*   esrc   = (int*)(ws + off); off += E;
    int*   bsum   = (int*)(ws + off); off += 64;
    int*   boff   = (int*)(ws + off); off += 64;
    unsigned short* Wt = (unsigned short*)(ws + off); off += 65536;               // 1024*128 bf16
    unsigned short* xl = (unsigned short*)(ws + off); off += (size_t)N * 256;     // N*512 bf16
    float* xrg    = ws + off; off += (size_t)N * 512;      // xr f32, overwritten by gat out
    float* h1 = zb;

    hipMemsetAsync(d_ws, 0, zero_floats * sizeof(float), stream);

    k_prep_w<<<CDIV(1024 * 128, 256), 256, 0, stream>>>(W_l, W_r, Wt);
    k_wc<<<1, 256, 0, stream>>>(W_ap, W_msg, b_ap, b_msg, Wzt, bc);
    k_xbf<<<CDIV(N * 64, 256), 256, 0, stream>>>(x, combin, N);
    k_scatter16<<<CDIV(E * 16, 256), 256, 0, stream>>>(ea, ei, agg16, cntI, E);
    k_aggfin<<<CDIV(N * 64, 256), 256, 0, stream>>>(agg16, cntI, W_ep, b_ep, combin, N);
    k_z<<<CDIV(N, 64), 256, 0, stream>>>(combin, Wzt, bc, zb, N);
    k_stats<<<256, 256, 0, stream>>>(zb, st_msg, N, 64);
    k_comb2<<<CDIV(N * 64, 256), 256, 0, stream>>>(zb, st_msg, g_msg, be_msg, combin, N);
    k_bsum<<<nb, 256, 0, stream>>>(cntI, bsum, N);
    k_boff<<<1, 64, 0, stream>>>(bsum, boff, nb);
    k_scan2<<<nb, 256, 0, stream>>>(cntI, boff, rowptr, N);
    k_fill<<<CDIV(E, 256), 256, 0, stream>>>(ei, rowptr, cursor, esrc, E);
    dim3 gx(CDIV(N, 64), 4);
    k_xlxr2<<<gx, 256, 0, stream>>>(combin, Wt, xl, xrg, N);
    k_gat<<<CDIV(N * 64, 256), 256, 0, stream>>>(xl, xrg, rowptr, esrc, att, b_gat, N);
    k_stats<<<256, 256, 0, stream>>>(xrg, st_gat, N, 512);
    k_post<<<CDIV(N, 32), 256, 0, stream>>>(xrg, st_gat, g_bn, be_bn, W_p1, b_p1, h1, N);
    k_stats<<<256, 256, 0, stream>>>(h1, st_p, N, 64);
    k_final<<<CDIV(N * 64, 256), 256, 0, stream>>>(h1, st_p, g_p, be_p, W_p2, b_p2,
                                                   (float*)d_out, N);
}

// Round 5
// 519.583 us; speedup vs baseline: 1.9822x; 1.2098x over previous
//
#include <hip/hip_runtime.h>
#include <hip/hip_bf16.h>

// ---------------------------------------------------------------------------
// GATv2 model pipeline. N=50000, E=400000, HID=64, H=8.
// Round 5: round-4 design with the Wzt workspace-size bug fixed
// (64*128 bf16 = 4096 floats, not 2048 — the overlap corrupted k_z's weights).
// ---------------------------------------------------------------------------

#define CDIV(a, b) (((a) + (b) - 1) / (b))

using f32x4 = __attribute__((ext_vector_type(4))) float;
using s16x8 = __attribute__((ext_vector_type(8))) short;

__device__ inline unsigned short f2bf(float f) {
    union { float f; unsigned u; } v; v.f = f;
    unsigned r = v.u + 0x7fff + ((v.u >> 16) & 1);   // round-nearest-even
    return (unsigned short)(r >> 16);
}
__device__ inline float bf_lo(unsigned w) {
    union { unsigned u; float f; } v; v.u = w << 16; return v.f;
}
__device__ inline float bf_hi(unsigned w) {
    union { unsigned u; float f; } v; v.u = w & 0xffff0000u; return v.f;
}

// Scatter raw edge_attr (16 ch) onto dst nodes + integer degree count.
__global__ void k_scatter16(const float* __restrict__ EA, const int* __restrict__ ei,
                            float* __restrict__ agg16, int* __restrict__ cntI, int E) {
    int t = blockIdx.x * blockDim.x + threadIdx.x;
    int e = t >> 4, ch = t & 15;
    if (e >= E) return;
    int dst = ei[E + e];
    atomicAdd(&agg16[(size_t)dst * 16 + ch], EA[(size_t)e * 16 + ch]);
    if (ch == 0) atomicAdd(&cntI[dst], 1);
}

// Wzt[c][0:64] = (W_ap@W_msg)[:,c], Wzt[c][64:128] = W_msg[:,c]; bc = b_ap@W_msg+b_msg.
__global__ void k_wc(const float* __restrict__ Wap, const float* __restrict__ Wmsg,
                     const float* __restrict__ bap, const float* __restrict__ bmsg,
                     unsigned short* __restrict__ Wzt, float* __restrict__ bc) {
    int t = threadIdx.x;
    for (int e = t; e < 4096; e += 256) {
        int i = e >> 6, c = e & 63;
        float s = 0.f;
        for (int j = 0; j < 64; ++j) s += Wap[i * 64 + j] * Wmsg[j * 64 + c];
        Wzt[c * 128 + i] = f2bf(s);
    }
    for (int e = t; e < 4096; e += 256) {
        int k = e >> 6, c = e & 63;
        Wzt[c * 128 + 64 + k] = f2bf(Wmsg[k * 64 + c]);
    }
    if (t < 64) {
        float s = bmsg[t];
        for (int j = 0; j < 64; ++j) s += bap[j] * Wmsg[j * 64 + t];
        bc[t] = s;
    }
}

// combin[n][0:64] = bf16(x[n])
__global__ void k_xbf(const float* __restrict__ x, unsigned short* __restrict__ combin, int N) {
    int idx = blockIdx.x * blockDim.x + threadIdx.x;
    if (idx >= N * 64) return;
    int n = idx >> 6, k = idx & 63;
    combin[(size_t)n * 128 + k] = f2bf(x[idx]);
}

// combin[n][64:128] = bf16(agg[n]) where agg = cnt>0 ? mean(ea)@W_ep + b_ep : 0.
__global__ void k_aggfin(const float* __restrict__ agg16, const int* __restrict__ cntI,
                         const float* __restrict__ Wep, const float* __restrict__ bep,
                         unsigned short* __restrict__ combin, int N) {
    int wid = (blockIdx.x * blockDim.x + threadIdx.x) >> 6;
    int lane = threadIdx.x & 63;
    if (wid >= N) return;
    int c = cntI[wid];
    float mval = (lane < 16 && c > 0) ? agg16[(size_t)wid * 16 + lane] / (float)c : 0.f;
    float acc = bep[lane];
#pragma unroll
    for (int j = 0; j < 16; ++j) {
        float mj = __shfl(mval, j, 64);
        acc = fmaf(mj, Wep[j * 64 + lane], acc);
    }
    if (c == 0) acc = 0.f;
    combin[(size_t)wid * 128 + 64 + lane] = f2bf(acc);
}

// MFMA GEMM1: z[N][64] = combin[N][128] @ Wzt^T + bc. Block 64 rows, 4 waves.
__global__ __launch_bounds__(256) void k_z(
    const unsigned short* __restrict__ combin, const unsigned short* __restrict__ Wzt,
    const float* __restrict__ bc, float* __restrict__ z, int N) {
    __shared__ unsigned short a_lds[64 * 128];
    __shared__ unsigned short b_lds[64 * 128];
    int t = threadIdx.x;
    int row0 = blockIdx.x * 64;
    for (int i = t; i < 1024; i += 256) {
        int row = i >> 4, seg = i & 15;
        int dsts = (row * 256 + ((seg * 16) ^ ((row & 7) << 4))) >> 1;
        int gr = row0 + row;
        s16x8 v = (s16x8)0;
        if (gr < N) v = *(const s16x8*)(combin + (size_t)gr * 128 + seg * 8);
        *(s16x8*)(a_lds + dsts) = v;
        *(s16x8*)(b_lds + dsts) = *(const s16x8*)(Wzt + (size_t)row * 128 + seg * 8);
    }
    __syncthreads();
    int w = t >> 6, l = t & 63, hi = l >> 4, lo = l & 15;
    int ar = w * 16 + lo;
    s16x8 a[4];
#pragma unroll
    for (int kk = 0; kk < 4; ++kk) {
        int byte = (kk * 64 + hi * 16) ^ ((ar & 7) << 4);
        a[kk] = *(const s16x8*)(a_lds + ((ar * 256 + byte) >> 1));
    }
#pragma unroll
    for (int cf = 0; cf < 4; ++cf) {
        int br = cf * 16 + lo;
        f32x4 acc = (f32x4){0.f, 0.f, 0.f, 0.f};
#pragma unroll
        for (int kk = 0; kk < 4; ++kk) {
            int byte = (kk * 64 + hi * 16) ^ ((br & 7) << 4);
            s16x8 b = *(const s16x8*)(b_lds + ((br * 256 + byte) >> 1));
            acc = __builtin_amdgcn_mfma_f32_16x16x32_bf16(a[kk], b, acc, 0, 0, 0);
        }
        int colg = cf * 16 + lo;
#pragma unroll
        for (int r = 0; r < 4; ++r) {
            int rowg = row0 + w * 16 + hi * 4 + r;
            if (rowg < N) z[(size_t)rowg * 64 + colg] = acc[r] + bc[colg];
        }
    }
}

// Per-channel sum & sumsq over rows (f32 input).
__global__ void k_stats(const float* __restrict__ X, float* __restrict__ sums,
                        int N, int C) {
    int t = blockIdx.x * blockDim.x + threadIdx.x;
    int c = t % C;
    int slice = t / C;
    int nslices = (gridDim.x * blockDim.x) / C;
    float ls = 0.f, lq = 0.f;
    for (int n = slice; n < N; n += nslices) {
        float v = X[(size_t)n * C + c];
        ls += v; lq += v * v;
    }
    atomicAdd(&sums[c], ls);
    atomicAdd(&sums[C + c], lq);
}

// Per-channel sum & sumsq for bf16 input with C=512 (2 channels per thread).
__global__ void k_stats_bf(const unsigned* __restrict__ X32, float* __restrict__ sums,
                           int N) {
    int t = blockIdx.x * blockDim.x + threadIdx.x;
    int cu = t & 255;
    int slice = t >> 8;
    int nslices = (gridDim.x * blockDim.x) >> 8;
    float s0 = 0.f, q0 = 0.f, s1 = 0.f, q1 = 0.f;
    for (int n = slice; n < N; n += nslices) {
        unsigned u = X32[(size_t)n * 256 + cu];
        float a = bf_lo(u), b = bf_hi(u);
        s0 += a; q0 += a * a; s1 += b; q1 += b * b;
    }
    atomicAdd(&sums[2 * cu], s0);
    atomicAdd(&sums[2 * cu + 1], s1);
    atomicAdd(&sums[512 + 2 * cu], q0);
    atomicAdd(&sums[512 + 2 * cu + 1], q1);
}

// sc[k] = g/sqrt(var+eps), sh[k] = be - mean*sc.  C=512.
__global__ void k_bnparam(const float* __restrict__ sums, const float* __restrict__ g,
                          const float* __restrict__ be, float* __restrict__ sc,
                          float* __restrict__ sh, int N) {
    int k = blockIdx.x * blockDim.x + threadIdx.x;
    if (k >= 512) return;
    float invN = 1.0f / (float)N;
    float mean = sums[k] * invN;
    float var = sums[512 + k] * invN - mean * mean;
    float s = g[k] * rsqrtf(var + 1e-5f);
    sc[k] = s;
    sh[k] = be[k] - mean * s;
}

// combin[n][0:64] = bf16(relu(bn(z[n])))  (in place; x part no longer needed)
__global__ void k_comb2(const float* __restrict__ z, const float* __restrict__ stats,
                        const float* __restrict__ g, const float* __restrict__ be,
                        unsigned short* __restrict__ combin, int N) {
    int idx = blockIdx.x * blockDim.x + threadIdx.x;
    if (idx >= N * 64) return;
    int n = idx >> 6, k = idx & 63;
    float invN = 1.0f / (float)N;
    float mean = stats[k] * invN;
    float var = stats[64 + k] * invN - mean * mean;
    float inv = rsqrtf(var + 1e-5f);
    float v = fmaxf((z[idx] - mean) * (inv * g[k]) + be[k], 0.f);
    combin[(size_t)n * 128 + k] = f2bf(v);
}

// ---- parallel exclusive scan of cntI -> rowptr (3 kernels) ----
__global__ void k_bsum(const int* __restrict__ cntI, int* __restrict__ bsum, int N) {
    int b = blockIdx.x, t = threadIdx.x;
    int base = b * 1024 + t * 4;
    int s = 0;
#pragma unroll
    for (int j = 0; j < 4; ++j) { int i = base + j; if (i < N) s += cntI[i]; }
    for (int off = 32; off; off >>= 1) s += __shfl_xor(s, off, 64);
    __shared__ int wsum[4];
    if ((t & 63) == 0) wsum[t >> 6] = s;
    __syncthreads();
    if (t == 0) bsum[b] = wsum[0] + wsum[1] + wsum[2] + wsum[3];
}
__global__ void k_boff(const int* __restrict__ bsum, int* __restrict__ boff, int nb) {
    int t = threadIdx.x;
    if (t < nb) { int s = 0; for (int j = 0; j < t; ++j) s += bsum[j]; boff[t] = s; }
}
__global__ void k_scan2(const int* __restrict__ cntI, const int* __restrict__ boff,
                        int* __restrict__ rowptr, int N) {
    int b = blockIdx.x, t = threadIdx.x;
    int base = b * 1024 + t * 4;
    int v[4]; int s = 0;
#pragma unroll
    for (int j = 0; j < 4; ++j) { int i = base + j; v[j] = (i < N) ? cntI[i] : 0; s += v[j]; }
    __shared__ int ls[256];
    ls[t] = s; __syncthreads();
    for (int off = 1; off < 256; off <<= 1) {
        int tv = (t >= (int)off) ? ls[t - off] : 0;
        __syncthreads(); ls[t] += tv; __syncthreads();
    }
    int run = ls[t] - s + boff[b];
#pragma unroll
    for (int j = 0; j < 4; ++j) { run += v[j]; int i = base + j; if (i < N) rowptr[i + 1] = run; }
    if (b == 0 && t == 0) rowptr[0] = 0;
}

// Scatter edge sources into CSR order (order within a segment is arbitrary).
__global__ void k_fill(const int* __restrict__ ei, const int* __restrict__ rowptr,
                       int* __restrict__ cursor, int* __restrict__ esrc, int E) {
    int e = blockIdx.x * blockDim.x + threadIdx.x;
    if (e >= E) return;
    int dst = ei[E + e];
    int pos = rowptr[dst] + atomicAdd(&cursor[dst], 1);
    esrc[pos] = ei[e];
}

// Wt[c][k] = bf16(c<512 ? W_l[k][c] : W_r[k][c-512]); [1024][128] bf16.
__global__ void k_prep_w(const float* __restrict__ Wl, const float* __restrict__ Wr,
                         unsigned short* __restrict__ Wt) {
    int idx = blockIdx.x * blockDim.x + threadIdx.x;
    if (idx >= 1024 * 128) return;
    int c = idx >> 7, k = idx & 127;
    float v = (c < 512) ? Wl[(size_t)k * 512 + c] : Wr[(size_t)k * 512 + (c - 512)];
    Wt[idx] = f2bf(v);
}

// Wp1t[c][k] = bf16(W_p1[k][c]); [64][512] bf16.
__global__ void k_prep_w1(const float* __restrict__ Wp1, unsigned short* __restrict__ Wp1t) {
    int idx = blockIdx.x * blockDim.x + threadIdx.x;
    if (idx >= 64 * 512) return;
    int c = idx >> 9, k = idx & 511;
    Wp1t[idx] = f2bf(Wp1[(size_t)k * 64 + c]);
}

// MFMA GEMM2: xlr[N][1024] = combin[N][128] @ Wt^T (bf16 out). 64 rows x 256 cols.
__global__ __launch_bounds__(256) void k_xlxr2(
    const unsigned short* __restrict__ combin, const unsigned short* __restrict__ Wt,
    unsigned short* __restrict__ xlr, int N) {
    __shared__ unsigned short a_lds[64 * 128];
    __shared__ unsigned short b_lds[256 * 128];
    int t = threadIdx.x;
    int row0 = blockIdx.x * 64;
    int c0 = blockIdx.y * 256;
    for (int i = t; i < 1024; i += 256) {
        int row = i >> 4, seg = i & 15;
        int dsts = (row * 256 + ((seg * 16) ^ ((row & 7) << 4))) >> 1;
        int gr = row0 + row;
        s16x8 v = (s16x8)0;
        if (gr < N) v = *(const s16x8*)(combin + (size_t)gr * 128 + seg * 8);
        *(s16x8*)(a_lds + dsts) = v;
    }
    for (int i = t; i < 4096; i += 256) {
        int row = i >> 4, seg = i & 15;
        int dsts = (row * 256 + ((seg * 16) ^ ((row & 7) << 4))) >> 1;
        *(s16x8*)(b_lds + dsts) = *(const s16x8*)(Wt + (size_t)(c0 + row) * 128 + seg * 8);
    }
    __syncthreads();
    int w = t >> 6, l = t & 63, hi = l >> 4, lo = l & 15;
    int ar = w * 16 + lo;
    s16x8 a[4];
#pragma unroll
    for (int kk = 0; kk < 4; ++kk) {
        int byte = (kk * 64 + hi * 16) ^ ((ar & 7) << 4);
        a[kk] = *(const s16x8*)(a_lds + ((ar * 256 + byte) >> 1));
    }
#pragma unroll
    for (int cf = 0; cf < 16; ++cf) {
        int br = cf * 16 + lo;
        f32x4 acc = (f32x4){0.f, 0.f, 0.f, 0.f};
#pragma unroll
        for (int kk = 0; kk < 4; ++kk) {
            int byte = (kk * 64 + hi * 16) ^ ((br & 7) << 4);
            s16x8 b = *(const s16x8*)(b_lds + ((br * 256 + byte) >> 1));
            acc = __builtin_amdgcn_mfma_f32_16x16x32_bf16(a[kk], b, acc, 0, 0, 0);
        }
        int colg = c0 + cf * 16 + lo;
#pragma unroll
        for (int r = 0; r < 4; ++r) {
            int rowg = row0 + w * 16 + hi * 4 + r;
            if (rowg < N) xlr[(size_t)rowg * 1024 + colg] = f2bf(acc[r]);
        }
    }
}

// GATv2 per-dst online softmax + weighted aggregation. One wave per dst node.
// xlr[n] = [xl (512) | xr (512)] bf16. Output gout bf16 (packed uints).
__global__ __launch_bounds__(256) void k_gat(
    const unsigned short* __restrict__ xlr, unsigned* __restrict__ gout32,
    const int* __restrict__ rowptr, const int* __restrict__ esrc,
    const float* __restrict__ att, const float* __restrict__ bg, int N) {
    int wid = (blockIdx.x * blockDim.x + threadIdx.x) >> 6;
    int lane = threadIdx.x & 63;
    if (wid >= N) return;
    int n = wid;
    float xrv[8], av[8], acc[8];
    {
        uint4 u = *(const uint4*)(xlr + (size_t)n * 1024 + 512 + lane * 8);
        xrv[0] = bf_lo(u.x); xrv[1] = bf_hi(u.x); xrv[2] = bf_lo(u.y); xrv[3] = bf_hi(u.y);
        xrv[4] = bf_lo(u.z); xrv[5] = bf_hi(u.z); xrv[6] = bf_lo(u.w); xrv[7] = bf_hi(u.w);
    }
#pragma unroll
    for (int j = 0; j < 8; ++j) { av[j] = att[lane * 8 + j]; acc[j] = 0.f; }
    float m = -1e30f, s = 0.f;
    int e0 = rowptr[n], e1 = rowptr[n + 1];
    for (int e = e0; e <= e1; ++e) {      // e == e1 -> self loop
        int src = (e < e1) ? esrc[e] : n;
        uint4 u = *(const uint4*)(xlr + (size_t)src * 1024 + lane * 8);
        float xlv[8] = {bf_lo(u.x), bf_hi(u.x), bf_lo(u.y), bf_hi(u.y),
                        bf_lo(u.z), bf_hi(u.z), bf_lo(u.w), bf_hi(u.w)};
        float ps = 0.f;
#pragma unroll
        for (int j = 0; j < 8; ++j) {
            float tv = xlv[j] + xrv[j];
            tv = (tv > 0.f) ? tv : 0.2f * tv;
            ps = fmaf(tv, av[j], ps);
        }
        ps += __shfl_xor(ps, 1, 64);
        ps += __shfl_xor(ps, 2, 64);
        ps += __shfl_xor(ps, 4, 64);       // per-head score, replicated in 8-lane group
        float mnew = fmaxf(m, ps);
        float sc = __expf(m - mnew);
        float w = __expf(ps - mnew);
        s = s * sc + w;
#pragma unroll
        for (int j = 0; j < 8; ++j) acc[j] = acc[j] * sc + w * xlv[j];
        m = mnew;
    }
    float invs = 1.0f / s;
    unsigned o[4];
#pragma unroll
    for (int p = 0; p < 4; ++p) {
        float lo = acc[2 * p] * invs + bg[lane * 8 + 2 * p];
        float hi = acc[2 * p + 1] * invs + bg[lane * 8 + 2 * p + 1];
        o[p] = (unsigned)f2bf(lo) | ((unsigned)f2bf(hi) << 16);
    }
    *(uint4*)(gout32 + (size_t)n * 256 + lane * 4) = make_uint4(o[0], o[1], o[2], o[3]);
}

// MFMA post-GEMM: h1[N][64] = relu(bn(gout)) @ W_p1 + b_p1. BN folded to sc/sh.
__global__ __launch_bounds__(256) void k_postm(
    const unsigned* __restrict__ gout32, const unsigned short* __restrict__ Wp1t,
    const float* __restrict__ sc, const float* __restrict__ sh,
    const float* __restrict__ bp1, float* __restrict__ h1, int N) {
    __shared__ unsigned short a_lds[64 * 128];
    __shared__ unsigned short b_lds[64 * 128];
    __shared__ float sc_l[512], sh_l[512];
    int t = threadIdx.x;
    for (int i = t; i < 512; i += 256) { sc_l[i] = sc[i]; sh_l[i] = sh[i]; }
    int row0 = blockIdx.x * 64;
    int w = t >> 6, l = t & 63, hi = l >> 4, lo = l & 15;
    int ar = w * 16 + lo;
    f32x4 acc[4];
#pragma unroll
    for (int cf = 0; cf < 4; ++cf) acc[cf] = (f32x4){0.f, 0.f, 0.f, 0.f};
    for (int kc = 0; kc < 4; ++kc) {
        __syncthreads();
        for (int i = t; i < 1024; i += 256) {
            int row = i >> 4, seg = i & 15;
            int dsts = (row * 256 + ((seg * 16) ^ ((row & 7) << 4))) >> 1;
            int gr = row0 + row;
            int k0 = kc * 128 + seg * 8;
            s16x8 v = (s16x8)0;
            if (gr < N) {
                uint4 u = *(const uint4*)(gout32 + (size_t)gr * 256 + (k0 >> 1));
                float f[8] = {bf_lo(u.x), bf_hi(u.x), bf_lo(u.y), bf_hi(u.y),
                              bf_lo(u.z), bf_hi(u.z), bf_lo(u.w), bf_hi(u.w)};
#pragma unroll
                for (int j = 0; j < 8; ++j) {
                    float y = fmaxf(fmaf(f[j], sc_l[k0 + j], sh_l[k0 + j]), 0.f);
                    v[j] = (short)f2bf(y);
                }
            }
            *(s16x8*)(a_lds + dsts) = v;
            *(s16x8*)(b_lds + dsts) = *(const s16x8*)(Wp1t + (size_t)row * 512 + k0);
        }
        __syncthreads();
        s16x8 a[4];
#pragma unroll
        for (int kk = 0; kk < 4; ++kk) {
            int byte = (kk * 64 + hi * 16) ^ ((ar & 7) << 4);
            a[kk] = *(const s16x8*)(a_lds + ((ar * 256 + byte) >> 1));
        }
#pragma unroll
        for (int cf = 0; cf < 4; ++cf) {
            int br = cf * 16 + lo;
#pragma unroll
            for (int kk = 0; kk < 4; ++kk) {
                int byte = (kk * 64 + hi * 16) ^ ((br & 7) << 4);
                s16x8 b = *(const s16x8*)(b_lds + ((br * 256 + byte) >> 1));
                acc[cf] = __builtin_amdgcn_mfma_f32_16x16x32_bf16(a[kk], b, acc[cf], 0, 0, 0);
            }
        }
    }
#pragma unroll
    for (int cf = 0; cf < 4; ++cf) {
        int colg = cf * 16 + lo;
#pragma unroll
        for (int r = 0; r < 4; ++r) {
            int rowg = row0 + w * 16 + hi * 4 + r;
            if (rowg < N) h1[(size_t)rowg * 64 + colg] = acc[cf][r] + bp1[colg];
        }
    }
}

// out[n] = relu(bn(h1 row)) . W_p2 + b_p2.  One wave per node.
__global__ void k_final(const float* __restrict__ h1, const float* __restrict__ stats,
                        const float* __restrict__ g, const float* __restrict__ be,
                        const float* __restrict__ Wp2, const float* __restrict__ bp2,
                        float* __restrict__ out, int N) {
    int wid = (blockIdx.x * blockDim.x + threadIdx.x) >> 6;
    int lane = threadIdx.x & 63;
    if (wid >= N) return;
    float invN = 1.0f / (float)N;
    float mean = stats[lane] * invN;
    float var = stats[64 + lane] * invN - mean * mean;
    float inv = rsqrtf(var + 1e-5f);
    float v = h1[(size_t)wid * 64 + lane];
    v = fmaxf((v - mean) * (inv * g[lane]) + be[lane], 0.f);
    float p = v * Wp2[lane];
#pragma unroll
    for (int off = 32; off; off >>= 1) p += __shfl_xor(p, off, 64);
    if (lane == 0) out[wid] = p + bp2[0];
}

extern "C" void kernel_launch(void* const* d_in, const int* in_sizes, int n_in,
                              void* d_out, int out_size, void* d_ws, size_t ws_size,
                              hipStream_t stream) {
    const float* x      = (const float*)d_in[0];
    const int*   ei     = (const int*)d_in[1];
    const float* ea     = (const float*)d_in[2];
    const float* W_ap   = (const float*)d_in[3];
    const float* b_ap   = (const float*)d_in[4];
    const float* W_ep   = (const float*)d_in[5];
    const float* b_ep   = (const float*)d_in[6];
    const float* W_msg  = (const float*)d_in[7];
    const float* b_msg  = (const float*)d_in[8];
    const float* g_msg  = (const float*)d_in[9];
    const float* be_msg = (const float*)d_in[10];
    const float* W_l    = (const float*)d_in[11];
    const float* W_r    = (const float*)d_in[12];
    const float* att    = (const float*)d_in[13];
    const float* b_gat  = (const float*)d_in[14];
    const float* g_bn   = (const float*)d_in[15];
    const float* be_bn  = (const float*)d_in[16];
    const float* W_p1   = (const float*)d_in[17];
    const float* b_p1   = (const float*)d_in[18];
    const float* g_p    = (const float*)d_in[19];
    const float* be_p   = (const float*)d_in[20];
    const float* W_p2   = (const float*)d_in[21];
    const float* b_p2   = (const float*)d_in[22];

    int N = in_sizes[0] / 64;
    int E = in_sizes[1] / 2;
    int nb = CDIV(N, 1024);

    // Workspace layout (floats). Zeroed prefix first.
    float* ws = (float*)d_ws;
    size_t off = 0;
    float* agg16  = ws + off; off += (size_t)N * 16;
    int*   cntI   = (int*)(ws + off); off += N;
    int*   cursor = (int*)(ws + off); off += N;
    float* st_msg = ws + off; off += 128;
    float* st_gat = ws + off; off += 1024;
    float* st_p   = ws + off; off += 128;
    size_t zero_floats = off;
    float* bn_sc  = ws + off; off += 512;
    float* bn_sh  = ws + off; off += 512;
    unsigned short* combin = (unsigned short*)(ws + off); off += (size_t)N * 64;  // N*128 bf16
    float* zb     = ws + off; off += (size_t)N * 64;       // z, later reused as h1
    unsigned short* Wzt = (unsigned short*)(ws + off); off += 4096;               // 64*128 bf16 = 4096 floats
    float* bc     = ws + off; off += 64;
    int*   rowptr = (int*)(ws + off); off += (size_t)(N + 1); off = (off + 3) & ~(size_t)3;
    int*   esrc   = (int*)(ws + off); off += E;
    int*   bsum   = (int*)(ws + off); off += 64;
    int*   boff   = (int*)(ws + off); off += 64;
    unsigned short* Wt  = (unsigned short*)(ws + off); off += 65536;              // 1024*128 bf16
    unsigned short* Wp1t = (unsigned short*)(ws + off); off += 16384;             // 64*512 bf16
    unsigned short* xlr = (unsigned short*)(ws + off); off += (size_t)N * 512;    // N*1024 bf16
    unsigned* gout32 = (unsigned*)(ws + off); off += (size_t)N * 256;             // N*512 bf16
    float* h1 = zb;

    hipMemsetAsync(d_ws, 0, zero_floats * sizeof(float), stream);

    k_prep_w<<<CDIV(1024 * 128, 256), 256, 0, stream>>>(W_l, W_r, Wt);
    k_prep_w1<<<CDIV(64 * 512, 256), 256, 0, stream>>>(W_p1, Wp1t);
    k_wc<<<1, 256, 0, stream>>>(W_ap, W_msg, b_ap, b_msg, Wzt, bc);
    k_xbf<<<CDIV(N * 64, 256), 256, 0, stream>>>(x, combin, N);
    k_scatter16<<<CDIV(E * 16, 256), 256, 0, stream>>>(ea, ei, agg16, cntI, E);
    k_aggfin<<<CDIV(N * 64, 256), 256, 0, stream>>>(agg16, cntI, W_ep, b_ep, combin, N);
    k_z<<<CDIV(N, 64), 256, 0, stream>>>(combin, Wzt, bc, zb, N);
    k_stats<<<256, 256, 0, stream>>>(zb, st_msg, N, 64);
    k_comb2<<<CDIV(N * 64, 256), 256, 0, stream>>>(zb, st_msg, g_msg, be_msg, combin, N);
    k_bsum<<<nb, 256, 0, stream>>>(cntI, bsum, N);
    k_boff<<<1, 64, 0, stream>>>(bsum, boff, nb);
    k_scan2<<<nb, 256, 0, stream>>>(cntI, boff, rowptr, N);
    k_fill<<<CDIV(E, 256), 256, 0, stream>>>(ei, rowptr, cursor, esrc, E);
    dim3 gx(CDIV(N, 64), 4);
    k_xlxr2<<<gx, 256, 0, stream>>>(combin, Wt, xlr, N);
    k_gat<<<CDIV(N * 64, 256), 256, 0, stream>>>(xlr, gout32, rowptr, esrc, att, b_gat, N);
    k_stats_bf<<<128, 256, 0, stream>>>(gout32, st_gat, N);
    k_bnparam<<<2, 256, 0, stream>>>(st_gat, g_bn, be_bn, bn_sc, bn_sh, N);
    k_postm<<<CDIV(N, 64), 256, 0, stream>>>(gout32, Wp1t, bn_sc, bn_sh, b_p1, h1, N);
    k_stats<<<256, 256, 0, stream>>>(h1, st_p, N, 64);
    k_final<<<CDIV(N * 64, 256), 256, 0, stream>>>(h1, st_p, g_p, be_p, W_p2, b_p2,
                                                   (float*)d_out, N);
}

// Round 6
// 407.640 us; speedup vs baseline: 2.5266x; 1.2746x over previous
//
#include <hip/hip_runtime.h>
#include <hip/hip_bf16.h>

// ---------------------------------------------------------------------------
// GATv2 model pipeline. N=50000, E=400000, HID=64, H=8.
// Round 6: fused BN stats (z-stats in k_z, h1-stats in k_postm epilogues),
// parallel uint4 gout-stats kernel (was 112us latency-bound at 128 blocks).
// ---------------------------------------------------------------------------

#define CDIV(a, b) (((a) + (b) - 1) / (b))

using f32x4 = __attribute__((ext_vector_type(4))) float;
using s16x8 = __attribute__((ext_vector_type(8))) short;

__device__ inline unsigned short f2bf(float f) {
    union { float f; unsigned u; } v; v.f = f;
    unsigned r = v.u + 0x7fff + ((v.u >> 16) & 1);   // round-nearest-even
    return (unsigned short)(r >> 16);
}
__device__ inline float bf_lo(unsigned w) {
    union { unsigned u; float f; } v; v.u = w << 16; return v.f;
}
__device__ inline float bf_hi(unsigned w) {
    union { unsigned u; float f; } v; v.u = w & 0xffff0000u; return v.f;
}

// Scatter raw edge_attr (16 ch) onto dst nodes + integer degree count.
__global__ void k_scatter16(const float* __restrict__ EA, const int* __restrict__ ei,
                            float* __restrict__ agg16, int* __restrict__ cntI, int E) {
    int t = blockIdx.x * blockDim.x + threadIdx.x;
    int e = t >> 4, ch = t & 15;
    if (e >= E) return;
    int dst = ei[E + e];
    atomicAdd(&agg16[(size_t)dst * 16 + ch], EA[(size_t)e * 16 + ch]);
    if (ch == 0) atomicAdd(&cntI[dst], 1);
}

// Wzt[c][0:64] = (W_ap@W_msg)[:,c], Wzt[c][64:128] = W_msg[:,c]; bc = b_ap@W_msg+b_msg.
__global__ void k_wc(const float* __restrict__ Wap, const float* __restrict__ Wmsg,
                     const float* __restrict__ bap, const float* __restrict__ bmsg,
                     unsigned short* __restrict__ Wzt, float* __restrict__ bc) {
    int t = threadIdx.x;
    for (int e = t; e < 4096; e += 256) {
        int i = e >> 6, c = e & 63;
        float s = 0.f;
        for (int j = 0; j < 64; ++j) s += Wap[i * 64 + j] * Wmsg[j * 64 + c];
        Wzt[c * 128 + i] = f2bf(s);
    }
    for (int e = t; e < 4096; e += 256) {
        int k = e >> 6, c = e & 63;
        Wzt[c * 128 + 64 + k] = f2bf(Wmsg[k * 64 + c]);
    }
    if (t < 64) {
        float s = bmsg[t];
        for (int j = 0; j < 64; ++j) s += bap[j] * Wmsg[j * 64 + t];
        bc[t] = s;
    }
}

// combin[n][0:64] = bf16(x[n])
__global__ void k_xbf(const float* __restrict__ x, unsigned short* __restrict__ combin, int N) {
    int idx = blockIdx.x * blockDim.x + threadIdx.x;
    if (idx >= N * 64) return;
    int n = idx >> 6, k = idx & 63;
    combin[(size_t)n * 128 + k] = f2bf(x[idx]);
}

// combin[n][64:128] = bf16(agg[n]) where agg = cnt>0 ? mean(ea)@W_ep + b_ep : 0.
__global__ void k_aggfin(const float* __restrict__ agg16, const int* __restrict__ cntI,
                         const float* __restrict__ Wep, const float* __restrict__ bep,
                         unsigned short* __restrict__ combin, int N) {
    int wid = (blockIdx.x * blockDim.x + threadIdx.x) >> 6;
    int lane = threadIdx.x & 63;
    if (wid >= N) return;
    int c = cntI[wid];
    float mval = (lane < 16 && c > 0) ? agg16[(size_t)wid * 16 + lane] / (float)c : 0.f;
    float acc = bep[lane];
#pragma unroll
    for (int j = 0; j < 16; ++j) {
        float mj = __shfl(mval, j, 64);
        acc = fmaf(mj, Wep[j * 64 + lane], acc);
    }
    if (c == 0) acc = 0.f;
    combin[(size_t)wid * 128 + 64 + lane] = f2bf(acc);
}

// MFMA GEMM1: z[N][64] = combin[N][128] @ Wzt^T + bc. Block 64 rows, 4 waves.
// Fused: per-channel sum/sumsq of z accumulated into sums[0..64)/[64..128).
__global__ __launch_bounds__(256) void k_z(
    const unsigned short* __restrict__ combin, const unsigned short* __restrict__ Wzt,
    const float* __restrict__ bc, float* __restrict__ z, float* __restrict__ sums, int N) {
    __shared__ unsigned short a_lds[64 * 128];
    __shared__ unsigned short b_lds[64 * 128];
    __shared__ float redS[64], redQ[64];
    int t = threadIdx.x;
    int row0 = blockIdx.x * 64;
    for (int i = t; i < 1024; i += 256) {
        int row = i >> 4, seg = i & 15;
        int dsts = (row * 256 + ((seg * 16) ^ ((row & 7) << 4))) >> 1;
        int gr = row0 + row;
        s16x8 v = (s16x8)0;
        if (gr < N) v = *(const s16x8*)(combin + (size_t)gr * 128 + seg * 8);
        *(s16x8*)(a_lds + dsts) = v;
        *(s16x8*)(b_lds + dsts) = *(const s16x8*)(Wzt + (size_t)row * 128 + seg * 8);
    }
    if (t < 64) { redS[t] = 0.f; redQ[t] = 0.f; }
    __syncthreads();
    int w = t >> 6, l = t & 63, hi = l >> 4, lo = l & 15;
    int ar = w * 16 + lo;
    s16x8 a[4];
#pragma unroll
    for (int kk = 0; kk < 4; ++kk) {
        int byte = (kk * 64 + hi * 16) ^ ((ar & 7) << 4);
        a[kk] = *(const s16x8*)(a_lds + ((ar * 256 + byte) >> 1));
    }
#pragma unroll
    for (int cf = 0; cf < 4; ++cf) {
        int br = cf * 16 + lo;
        f32x4 acc = (f32x4){0.f, 0.f, 0.f, 0.f};
#pragma unroll
        for (int kk = 0; kk < 4; ++kk) {
            int byte = (kk * 64 + hi * 16) ^ ((br & 7) << 4);
            s16x8 b = *(const s16x8*)(b_lds + ((br * 256 + byte) >> 1));
            acc = __builtin_amdgcn_mfma_f32_16x16x32_bf16(a[kk], b, acc, 0, 0, 0);
        }
        int colg = cf * 16 + lo;
        float bcv = bc[colg];
        float sv = 0.f, qv = 0.f;
#pragma unroll
        for (int r = 0; r < 4; ++r) {
            int rowg = row0 + w * 16 + hi * 4 + r;
            if (rowg < N) {
                float v = acc[r] + bcv;
                z[(size_t)rowg * 64 + colg] = v;
                sv += v; qv += v * v;
            }
        }
        atomicAdd(&redS[colg], sv);
        atomicAdd(&redQ[colg], qv);
    }
    __syncthreads();
    if (t < 64) {
        atomicAdd(&sums[t], redS[t]);
        atomicAdd(&sums[64 + t], redQ[t]);
    }
}

// Per-channel sum & sumsq for bf16 gout, C=512. 256 blocks; uint4 loads;
// LDS block reduction then one 1024-float atomic set per block.
__global__ __launch_bounds__(256) void k_statsg(const uint4* __restrict__ X,
                                                float* __restrict__ sums, int N) {
    __shared__ float redS[512], redQ[512];
    int t = threadIdx.x;
    for (int i = t; i < 512; i += 256) { redS[i] = 0.f; redQ[i] = 0.f; }
    __syncthreads();
    int qu = t & 63;                              // uint4 index within row
    int slice = (blockIdx.x << 2) | (t >> 6);
    int nsl = gridDim.x << 2;
    float s[8], q[8];
#pragma unroll
    for (int j = 0; j < 8; ++j) { s[j] = 0.f; q[j] = 0.f; }
    for (int n = slice; n < N; n += nsl) {
        uint4 u = X[(size_t)n * 64 + qu];
        unsigned uu[4] = {u.x, u.y, u.z, u.w};
#pragma unroll
        for (int k2 = 0; k2 < 4; ++k2) {
            float a = bf_lo(uu[k2]), b = bf_hi(uu[k2]);
            s[2 * k2] += a; q[2 * k2] += a * a;
            s[2 * k2 + 1] += b; q[2 * k2 + 1] += b * b;
        }
    }
#pragma unroll
    for (int j = 0; j < 8; ++j) {
        atomicAdd(&redS[qu * 8 + j], s[j]);
        atomicAdd(&redQ[qu * 8 + j], q[j]);
    }
    __syncthreads();
    for (int i = t; i < 512; i += 256) {
        atomicAdd(&sums[i], redS[i]);
        atomicAdd(&sums[512 + i], redQ[i]);
    }
}

// sc[k] = g/sqrt(var+eps), sh[k] = be - mean*sc.  C=512.
__global__ void k_bnparam(const float* __restrict__ sums, const float* __restrict__ g,
                          const float* __restrict__ be, float* __restrict__ sc,
                          float* __restrict__ sh, int N) {
    int k = blockIdx.x * blockDim.x + threadIdx.x;
    if (k >= 512) return;
    float invN = 1.0f / (float)N;
    float mean = sums[k] * invN;
    float var = sums[512 + k] * invN - mean * mean;
    float s = g[k] * rsqrtf(var + 1e-5f);
    sc[k] = s;
    sh[k] = be[k] - mean * s;
}

// combin[n][0:64] = bf16(relu(bn(z[n])))  (in place; x part no longer needed)
__global__ void k_comb2(const float* __restrict__ z, const float* __restrict__ stats,
                        const float* __restrict__ g, const float* __restrict__ be,
                        unsigned short* __restrict__ combin, int N) {
    int idx = blockIdx.x * blockDim.x + threadIdx.x;
    if (idx >= N * 64) return;
    int n = idx >> 6, k = idx & 63;
    float invN = 1.0f / (float)N;
    float mean = stats[k] * invN;
    float var = stats[64 + k] * invN - mean * mean;
    float inv = rsqrtf(var + 1e-5f);
    float v = fmaxf((z[idx] - mean) * (inv * g[k]) + be[k], 0.f);
    combin[(size_t)n * 128 + k] = f2bf(v);
}

// ---- parallel exclusive scan of cntI -> rowptr (3 kernels) ----
__global__ void k_bsum(const int* __restrict__ cntI, int* __restrict__ bsum, int N) {
    int b = blockIdx.x, t = threadIdx.x;
    int base = b * 1024 + t * 4;
    int s = 0;
#pragma unroll
    for (int j = 0; j < 4; ++j) { int i = base + j; if (i < N) s += cntI[i]; }
    for (int off = 32; off; off >>= 1) s += __shfl_xor(s, off, 64);
    __shared__ int wsum[4];
    if ((t & 63) == 0) wsum[t >> 6] = s;
    __syncthreads();
    if (t == 0) bsum[b] = wsum[0] + wsum[1] + wsum[2] + wsum[3];
}
__global__ void k_boff(const int* __restrict__ bsum, int* __restrict__ boff, int nb) {
    int t = threadIdx.x;
    if (t < nb) { int s = 0; for (int j = 0; j < t; ++j) s += bsum[j]; boff[t] = s; }
}
__global__ void k_scan2(const int* __restrict__ cntI, const int* __restrict__ boff,
                        int* __restrict__ rowptr, int N) {
    int b = blockIdx.x, t = threadIdx.x;
    int base = b * 1024 + t * 4;
    int v[4]; int s = 0;
#pragma unroll
    for (int j = 0; j < 4; ++j) { int i = base + j; v[j] = (i < N) ? cntI[i] : 0; s += v[j]; }
    __shared__ int ls[256];
    ls[t] = s; __syncthreads();
    for (int off = 1; off < 256; off <<= 1) {
        int tv = (t >= (int)off) ? ls[t - off] : 0;
        __syncthreads(); ls[t] += tv; __syncthreads();
    }
    int run = ls[t] - s + boff[b];
#pragma unroll
    for (int j = 0; j < 4; ++j) { run += v[j]; int i = base + j; if (i < N) rowptr[i + 1] = run; }
    if (b == 0 && t == 0) rowptr[0] = 0;
}

// Scatter edge sources into CSR order (order within a segment is arbitrary).
__global__ void k_fill(const int* __restrict__ ei, const int* __restrict__ rowptr,
                       int* __restrict__ cursor, int* __restrict__ esrc, int E) {
    int e = blockIdx.x * blockDim.x + threadIdx.x;
    if (e >= E) return;
    int dst = ei[E + e];
    int pos = rowptr[dst] + atomicAdd(&cursor[dst], 1);
    esrc[pos] = ei[e];
}

// Wt[c][k] = bf16(c<512 ? W_l[k][c] : W_r[k][c-512]); [1024][128] bf16.
__global__ void k_prep_w(const float* __restrict__ Wl, const float* __restrict__ Wr,
                         unsigned short* __restrict__ Wt) {
    int idx = blockIdx.x * blockDim.x + threadIdx.x;
    if (idx >= 1024 * 128) return;
    int c = idx >> 7, k = idx & 127;
    float v = (c < 512) ? Wl[(size_t)k * 512 + c] : Wr[(size_t)k * 512 + (c - 512)];
    Wt[idx] = f2bf(v);
}

// Wp1t[c][k] = bf16(W_p1[k][c]); [64][512] bf16.
__global__ void k_prep_w1(const float* __restrict__ Wp1, unsigned short* __restrict__ Wp1t) {
    int idx = blockIdx.x * blockDim.x + threadIdx.x;
    if (idx >= 64 * 512) return;
    int c = idx >> 9, k = idx & 511;
    Wp1t[idx] = f2bf(Wp1[(size_t)k * 64 + c]);
}

// MFMA GEMM2: xlr[N][1024] = combin[N][128] @ Wt^T (bf16 out). 64 rows x 256 cols.
__global__ __launch_bounds__(256) void k_xlxr2(
    const unsigned short* __restrict__ combin, const unsigned short* __restrict__ Wt,
    unsigned short* __restrict__ xlr, int N) {
    __shared__ unsigned short a_lds[64 * 128];
    __shared__ unsigned short b_lds[256 * 128];
    int t = threadIdx.x;
    int row0 = blockIdx.x * 64;
    int c0 = blockIdx.y * 256;
    for (int i = t; i < 1024; i += 256) {
        int row = i >> 4, seg = i & 15;
        int dsts = (row * 256 + ((seg * 16) ^ ((row & 7) << 4))) >> 1;
        int gr = row0 + row;
        s16x8 v = (s16x8)0;
        if (gr < N) v = *(const s16x8*)(combin + (size_t)gr * 128 + seg * 8);
        *(s16x8*)(a_lds + dsts) = v;
    }
    for (int i = t; i < 4096; i += 256) {
        int row = i >> 4, seg = i & 15;
        int dsts = (row * 256 + ((seg * 16) ^ ((row & 7) << 4))) >> 1;
        *(s16x8*)(b_lds + dsts) = *(const s16x8*)(Wt + (size_t)(c0 + row) * 128 + seg * 8);
    }
    __syncthreads();
    int w = t >> 6, l = t & 63, hi = l >> 4, lo = l & 15;
    int ar = w * 16 + lo;
    s16x8 a[4];
#pragma unroll
    for (int kk = 0; kk < 4; ++kk) {
        int byte = (kk * 64 + hi * 16) ^ ((ar & 7) << 4);
        a[kk] = *(const s16x8*)(a_lds + ((ar * 256 + byte) >> 1));
    }
#pragma unroll
    for (int cf = 0; cf < 16; ++cf) {
        int br = cf * 16 + lo;
        f32x4 acc = (f32x4){0.f, 0.f, 0.f, 0.f};
#pragma unroll
        for (int kk = 0; kk < 4; ++kk) {
            int byte = (kk * 64 + hi * 16) ^ ((br & 7) << 4);
            s16x8 b = *(const s16x8*)(b_lds + ((br * 256 + byte) >> 1));
            acc = __builtin_amdgcn_mfma_f32_16x16x32_bf16(a[kk], b, acc, 0, 0, 0);
        }
        int colg = c0 + cf * 16 + lo;
#pragma unroll
        for (int r = 0; r < 4; ++r) {
            int rowg = row0 + w * 16 + hi * 4 + r;
            if (rowg < N) xlr[(size_t)rowg * 1024 + colg] = f2bf(acc[r]);
        }
    }
}

// GATv2 per-dst online softmax + weighted aggregation. One wave per dst node.
// xlr[n] = [xl (512) | xr (512)] bf16. Output gout bf16 (packed uints).
__global__ __launch_bounds__(256) void k_gat(
    const unsigned short* __restrict__ xlr, unsigned* __restrict__ gout32,
    const int* __restrict__ rowptr, const int* __restrict__ esrc,
    const float* __restrict__ att, const float* __restrict__ bg, int N) {
    int wid = (blockIdx.x * blockDim.x + threadIdx.x) >> 6;
    int lane = threadIdx.x & 63;
    if (wid >= N) return;
    int n = wid;
    float xrv[8], av[8], acc[8];
    {
        uint4 u = *(const uint4*)(xlr + (size_t)n * 1024 + 512 + lane * 8);
        xrv[0] = bf_lo(u.x); xrv[1] = bf_hi(u.x); xrv[2] = bf_lo(u.y); xrv[3] = bf_hi(u.y);
        xrv[4] = bf_lo(u.z); xrv[5] = bf_hi(u.z); xrv[6] = bf_lo(u.w); xrv[7] = bf_hi(u.w);
    }
#pragma unroll
    for (int j = 0; j < 8; ++j) { av[j] = att[lane * 8 + j]; acc[j] = 0.f; }
    float m = -1e30f, s = 0.f;
    int e0 = rowptr[n], e1 = rowptr[n + 1];
    for (int e = e0; e <= e1; ++e) {      // e == e1 -> self loop
        int src = (e < e1) ? esrc[e] : n;
        uint4 u = *(const uint4*)(xlr + (size_t)src * 1024 + lane * 8);
        float xlv[8] = {bf_lo(u.x), bf_hi(u.x), bf_lo(u.y), bf_hi(u.y),
                        bf_lo(u.z), bf_hi(u.z), bf_lo(u.w), bf_hi(u.w)};
        float ps = 0.f;
#pragma unroll
        for (int j = 0; j < 8; ++j) {
            float tv = xlv[j] + xrv[j];
            tv = (tv > 0.f) ? tv : 0.2f * tv;
            ps = fmaf(tv, av[j], ps);
        }
        ps += __shfl_xor(ps, 1, 64);
        ps += __shfl_xor(ps, 2, 64);
        ps += __shfl_xor(ps, 4, 64);       // per-head score, replicated in 8-lane group
        float mnew = fmaxf(m, ps);
        float sc = __expf(m - mnew);
        float w = __expf(ps - mnew);
        s = s * sc + w;
#pragma unroll
        for (int j = 0; j < 8; ++j) acc[j] = acc[j] * sc + w * xlv[j];
        m = mnew;
    }
    float invs = 1.0f / s;
    unsigned o[4];
#pragma unroll
    for (int p = 0; p < 4; ++p) {
        float lo = acc[2 * p] * invs + bg[lane * 8 + 2 * p];
        float hi = acc[2 * p + 1] * invs + bg[lane * 8 + 2 * p + 1];
        o[p] = (unsigned)f2bf(lo) | ((unsigned)f2bf(hi) << 16);
    }
    *(uint4*)(gout32 + (size_t)n * 256 + lane * 4) = make_uint4(o[0], o[1], o[2], o[3]);
}

// MFMA post-GEMM: h1[N][64] = relu(bn(gout)) @ W_p1 + b_p1. BN folded to sc/sh.
// Fused: per-channel sum/sumsq of h1 into sums[0..64)/[64..128).
__global__ __launch_bounds__(256) void k_postm(
    const unsigned* __restrict__ gout32, const unsigned short* __restrict__ Wp1t,
    const float* __restrict__ sc, const float* __restrict__ sh,
    const float* __restrict__ bp1, float* __restrict__ h1, float* __restrict__ sums,
    int N) {
    __shared__ unsigned short a_lds[64 * 128];
    __shared__ unsigned short b_lds[64 * 128];
    __shared__ float sc_l[512], sh_l[512];
    __shared__ float redS[64], redQ[64];
    int t = threadIdx.x;
    for (int i = t; i < 512; i += 256) { sc_l[i] = sc[i]; sh_l[i] = sh[i]; }
    if (t < 64) { redS[t] = 0.f; redQ[t] = 0.f; }
    int row0 = blockIdx.x * 64;
    int w = t >> 6, l = t & 63, hi = l >> 4, lo = l & 15;
    int ar = w * 16 + lo;
    f32x4 acc[4];
#pragma unroll
    for (int cf = 0; cf < 4; ++cf) acc[cf] = (f32x4){0.f, 0.f, 0.f, 0.f};
    for (int kc = 0; kc < 4; ++kc) {
        __syncthreads();
        for (int i = t; i < 1024; i += 256) {
            int row = i >> 4, seg = i & 15;
            int dsts = (row * 256 + ((seg * 16) ^ ((row & 7) << 4))) >> 1;
            int gr = row0 + row;
            int k0 = kc * 128 + seg * 8;
            s16x8 v = (s16x8)0;
            if (gr < N) {
                uint4 u = *(const uint4*)(gout32 + (size_t)gr * 256 + (k0 >> 1));
                float f[8] = {bf_lo(u.x), bf_hi(u.x), bf_lo(u.y), bf_hi(u.y),
                              bf_lo(u.z), bf_hi(u.z), bf_lo(u.w), bf_hi(u.w)};
#pragma unroll
                for (int j = 0; j < 8; ++j) {
                    float y = fmaxf(fmaf(f[j], sc_l[k0 + j], sh_l[k0 + j]), 0.f);
                    v[j] = (short)f2bf(y);
                }
            }
            *(s16x8*)(a_lds + dsts) = v;
            *(s16x8*)(b_lds + dsts) = *(const s16x8*)(Wp1t + (size_t)row * 512 + k0);
        }
        __syncthreads();
        s16x8 a[4];
#pragma unroll
        for (int kk = 0; kk < 4; ++kk) {
            int byte = (kk * 64 + hi * 16) ^ ((ar & 7) << 4);
            a[kk] = *(const s16x8*)(a_lds + ((ar * 256 + byte) >> 1));
        }
#pragma unroll
        for (int cf = 0; cf < 4; ++cf) {
            int br = cf * 16 + lo;
#pragma unroll
            for (int kk = 0; kk < 4; ++kk) {
                int byte = (kk * 64 + hi * 16) ^ ((br & 7) << 4);
                s16x8 b = *(const s16x8*)(b_lds + ((br * 256 + byte) >> 1));
                acc[cf] = __builtin_amdgcn_mfma_f32_16x16x32_bf16(a[kk], b, acc[cf], 0, 0, 0);
            }
        }
    }
#pragma unroll
    for (int cf = 0; cf < 4; ++cf) {
        int colg = cf * 16 + lo;
        float bv = bp1[colg];
        float sv = 0.f, qv = 0.f;
#pragma unroll
        for (int r = 0; r < 4; ++r) {
            int rowg = row0 + w * 16 + hi * 4 + r;
            if (rowg < N) {
                float v = acc[cf][r] + bv;
                h1[(size_t)rowg * 64 + colg] = v;
                sv += v; qv += v * v;
            }
        }
        atomicAdd(&redS[colg], sv);
        atomicAdd(&redQ[colg], qv);
    }
    __syncthreads();
    if (t < 64) {
        atomicAdd(&sums[t], redS[t]);
        atomicAdd(&sums[64 + t], redQ[t]);
    }
}

// out[n] = relu(bn(h1 row)) . W_p2 + b_p2.  One wave per node.
__global__ void k_final(const float* __restrict__ h1, const float* __restrict__ stats,
                        const float* __restrict__ g, const float* __restrict__ be,
                        const float* __restrict__ Wp2, const float* __restrict__ bp2,
                        float* __restrict__ out, int N) {
    int wid = (blockIdx.x * blockDim.x + threadIdx.x) >> 6;
    int lane = threadIdx.x & 63;
    if (wid >= N) return;
    float invN = 1.0f / (float)N;
    float mean = stats[lane] * invN;
    float var = stats[64 + lane] * invN - mean * mean;
    float inv = rsqrtf(var + 1e-5f);
    float v = h1[(size_t)wid * 64 + lane];
    v = fmaxf((v - mean) * (inv * g[lane]) + be[lane], 0.f);
    float p = v * Wp2[lane];
#pragma unroll
    for (int off = 32; off; off >>= 1) p += __shfl_xor(p, off, 64);
    if (lane == 0) out[wid] = p + bp2[0];
}

extern "C" void kernel_launch(void* const* d_in, const int* in_sizes, int n_in,
                              void* d_out, int out_size, void* d_ws, size_t ws_size,
                              hipStream_t stream) {
    const float* x      = (const float*)d_in[0];
    const int*   ei     = (const int*)d_in[1];
    const float* ea     = (const float*)d_in[2];
    const float* W_ap   = (const float*)d_in[3];
    const float* b_ap   = (const float*)d_in[4];
    const float* W_ep   = (const float*)d_in[5];
    const float* b_ep   = (const float*)d_in[6];
    const float* W_msg  = (const float*)d_in[7];
    const float* b_msg  = (const float*)d_in[8];
    const float* g_msg  = (const float*)d_in[9];
    const float* be_msg = (const float*)d_in[10];
    const float* W_l    = (const float*)d_in[11];
    const float* W_r    = (const float*)d_in[12];
    const float* att    = (const float*)d_in[13];
    const float* b_gat  = (const float*)d_in[14];
    const float* g_bn   = (const float*)d_in[15];
    const float* be_bn  = (const float*)d_in[16];
    const float* W_p1   = (const float*)d_in[17];
    const float* b_p1   = (const float*)d_in[18];
    const float* g_p    = (const float*)d_in[19];
    const float* be_p   = (const float*)d_in[20];
    const float* W_p2   = (const float*)d_in[21];
    const float* b_p2   = (const float*)d_in[22];

    int N = in_sizes[0] / 64;
    int E = in_sizes[1] / 2;
    int nb = CDIV(N, 1024);

    // Workspace layout (floats). Zeroed prefix first.
    float* ws = (float*)d_ws;
    size_t off = 0;
    float* agg16  = ws + off; off += (size_t)N * 16;
    int*   cntI   = (int*)(ws + off); off += N;
    int*   cursor = (int*)(ws + off); off += N;
    float* st_msg = ws + off; off += 128;
    float* st_gat = ws + off; off += 1024;
    float* st_p   = ws + off; off += 128;
    size_t zero_floats = off;
    float* bn_sc  = ws + off; off += 512;
    float* bn_sh  = ws + off; off += 512;
    unsigned short* combin = (unsigned short*)(ws + off); off += (size_t)N * 64;  // N*128 bf16
    float* zb     = ws + off; off += (size_t)N * 64;       // z, later reused as h1
    unsigned short* Wzt = (unsigned short*)(ws + off); off += 4096;               // 64*128 bf16 = 4096 floats
    float* bc     = ws + off; off += 64;
    int*   rowptr = (int*)(ws + off); off += (size_t)(N + 1); off = (off + 3) & ~(size_t)3;
    int*   esrc   = (int*)(ws + off); off += E;
    int*   bsum   = (int*)(ws + off); off += 64;
    int*   boff   = (int*)(ws + off); off += 64;
    unsigned short* Wt  = (unsigned short*)(ws + off); off += 65536;              // 1024*128 bf16
    unsigned short* Wp1t = (unsigned short*)(ws + off); off += 16384;             // 64*512 bf16
    unsigned short* xlr = (unsigned short*)(ws + off); off += (size_t)N * 512;    // N*1024 bf16
    unsigned* gout32 = (unsigned*)(ws + off); off += (size_t)N * 256;             // N*512 bf16
    float* h1 = zb;

    hipMemsetAsync(d_ws, 0, zero_floats * sizeof(float), stream);

    k_prep_w<<<CDIV(1024 * 128, 256), 256, 0, stream>>>(W_l, W_r, Wt);
    k_prep_w1<<<CDIV(64 * 512, 256), 256, 0, stream>>>(W_p1, Wp1t);
    k_wc<<<1, 256, 0, stream>>>(W_ap, W_msg, b_ap, b_msg, Wzt, bc);
    k_xbf<<<CDIV(N * 64, 256), 256, 0, stream>>>(x, combin, N);
    k_scatter16<<<CDIV(E * 16, 256), 256, 0, stream>>>(ea, ei, agg16, cntI, E);
    k_aggfin<<<CDIV(N * 64, 256), 256, 0, stream>>>(agg16, cntI, W_ep, b_ep, combin, N);
    k_z<<<CDIV(N, 64), 256, 0, stream>>>(combin, Wzt, bc, zb, st_msg, N);
    k_comb2<<<CDIV(N * 64, 256), 256, 0, stream>>>(zb, st_msg, g_msg, be_msg, combin, N);
    k_bsum<<<nb, 256, 0, stream>>>(cntI, bsum, N);
    k_boff<<<1, 64, 0, stream>>>(bsum, boff, nb);
    k_scan2<<<nb, 256, 0, stream>>>(cntI, boff, rowptr, N);
    k_fill<<<CDIV(E, 256), 256, 0, stream>>>(ei, rowptr, cursor, esrc, E);
    dim3 gx(CDIV(N, 64), 4);
    k_xlxr2<<<gx, 256, 0, stream>>>(combin, Wt, xlr, N);
    k_gat<<<CDIV(N * 64, 256), 256, 0, stream>>>(xlr, gout32, rowptr, esrc, att, b_gat, N);
    k_statsg<<<256, 256, 0, stream>>>((const uint4*)gout32, st_gat, N);
    k_bnparam<<<2, 256, 0, stream>>>(st_gat, g_bn, be_bn, bn_sc, bn_sh, N);
    k_postm<<<CDIV(N, 64), 256, 0, stream>>>(gout32, Wp1t, bn_sc, bn_sh, b_p1, h1, st_p, N);
    k_final<<<CDIV(N * 64, 256), 256, 0, stream>>>(h1, st_p, g_p, be_p, W_p2, b_p2,
                                                   (float*)d_out, N);
}

// Round 8
// 400.734 us; speedup vs baseline: 2.5701x; 1.0172x over previous
//
#include <hip/hip_runtime.h>
#include <hip/hip_bf16.h>

// ---------------------------------------------------------------------------
// GATv2 model pipeline. N=50000, E=400000, HID=64, H=8.
// Round 8: round-7 design with k_combin's divergent-shfl bug fixed
// (ds_bpermute from inactive lanes is undefined on CDNA -> pack via
//  unconditional shuffles + per-lane select).
// ---------------------------------------------------------------------------

#define CDIV(a, b) (((a) + (b) - 1) / (b))

using f32x4 = __attribute__((ext_vector_type(4))) float;
using s16x8 = __attribute__((ext_vector_type(8))) short;

__device__ inline unsigned short f2bf(float f) {
    union { float f; unsigned u; } v; v.f = f;
    unsigned r = v.u + 0x7fff + ((v.u >> 16) & 1);   // round-nearest-even
    return (unsigned short)(r >> 16);
}
__device__ inline float bf_lo(unsigned w) {
    union { unsigned u; float f; } v; v.u = w << 16; return v.f;
}
__device__ inline float bf_hi(unsigned w) {
    union { unsigned u; float f; } v; v.u = w & 0xffff0000u; return v.f;
}
__device__ inline void unp8(uint4 u, float* v) {
    v[0] = bf_lo(u.x); v[1] = bf_hi(u.x); v[2] = bf_lo(u.y); v[3] = bf_hi(u.y);
    v[4] = bf_lo(u.z); v[5] = bf_hi(u.z); v[6] = bf_lo(u.w); v[7] = bf_hi(u.w);
}

// Scatter raw edge_attr (16 ch) onto dst nodes + integer degree count.
__global__ void k_scatter16(const float* __restrict__ EA, const int* __restrict__ ei,
                            float* __restrict__ agg16, int* __restrict__ cntI, int E) {
    int t = blockIdx.x * blockDim.x + threadIdx.x;
    int e = t >> 4, ch = t & 15;
    if (e >= E) return;
    int dst = ei[E + e];
    atomicAdd(&agg16[(size_t)dst * 16 + ch], EA[(size_t)e * 16 + ch]);
    if (ch == 0) atomicAdd(&cntI[dst], 1);
}

// Wzt[c][0:64] = (W_ap@W_msg)[:,c], Wzt[c][64:128] = W_msg[:,c]; bc = b_ap@W_msg+b_msg.
__global__ void k_wc(const float* __restrict__ Wap, const float* __restrict__ Wmsg,
                     const float* __restrict__ bap, const float* __restrict__ bmsg,
                     unsigned short* __restrict__ Wzt, float* __restrict__ bc) {
    int t = threadIdx.x;
    for (int e = t; e < 4096; e += 256) {
        int i = e >> 6, c = e & 63;
        float s = 0.f;
        for (int j = 0; j < 64; ++j) s += Wap[i * 64 + j] * Wmsg[j * 64 + c];
        Wzt[c * 128 + i] = f2bf(s);
    }
    for (int e = t; e < 4096; e += 256) {
        int k = e >> 6, c = e & 63;
        Wzt[c * 128 + 64 + k] = f2bf(Wmsg[k * 64 + c]);
    }
    if (t < 64) {
        float s = bmsg[t];
        for (int j = 0; j < 64; ++j) s += bap[j] * Wmsg[j * 64 + t];
        bc[t] = s;
    }
}

// One wave per node: combin row = [bf16(x) | bf16(agg)], packed uint stores.
// agg = cnt>0 ? mean(ea)@W_ep + b_ep : 0.  All shuffles wave-uniform (no
// divergence around ds_bpermute).
__global__ void k_combin(const float* __restrict__ x, const float* __restrict__ agg16,
                         const int* __restrict__ cntI, const float* __restrict__ Wep,
                         const float* __restrict__ bep, unsigned* __restrict__ combin32,
                         int N) {
    int wid = (blockIdx.x * blockDim.x + threadIdx.x) >> 6;
    int lane = threadIdx.x & 63;
    if (wid >= N) return;
    int c = cntI[wid];
    float mval = (lane < 16 && c > 0) ? agg16[(size_t)wid * 16 + lane] / (float)c : 0.f;
    float aggv = bep[lane];
#pragma unroll
    for (int j = 0; j < 16; ++j) {
        float mj = __shfl(mval, j, 64);
        aggv = fmaf(mj, Wep[j * 64 + lane], aggv);
    }
    if (c == 0) aggv = 0.f;
    float xv = x[(size_t)wid * 64 + lane];
    int i0 = (lane & 31) * 2;               // uniform formula for both halves
    float ax = __shfl(xv, i0, 64);
    float bx = __shfl(xv, i0 + 1, 64);
    float aa = __shfl(aggv, i0, 64);
    float ba = __shfl(aggv, i0 + 1, 64);
    float a = (lane < 32) ? ax : aa;
    float b = (lane < 32) ? bx : ba;
    combin32[(size_t)wid * 64 + lane] = (unsigned)f2bf(a) | ((unsigned)f2bf(b) << 16);
}

// MFMA GEMM1: z[N][64] = combin[N][128] @ Wzt^T + bc. Block 64 rows, 4 waves.
// Fused: per-channel sum/sumsq of z accumulated into sums[0..64)/[64..128).
__global__ __launch_bounds__(256) void k_z(
    const unsigned short* __restrict__ combin, const unsigned short* __restrict__ Wzt,
    const float* __restrict__ bc, float* __restrict__ z, float* __restrict__ sums, int N) {
    __shared__ unsigned short a_lds[64 * 128];
    __shared__ unsigned short b_lds[64 * 128];
    __shared__ float redS[64], redQ[64];
    int t = threadIdx.x;
    int row0 = blockIdx.x * 64;
    for (int i = t; i < 1024; i += 256) {
        int row = i >> 4, seg = i & 15;
        int dsts = (row * 256 + ((seg * 16) ^ ((row & 7) << 4))) >> 1;
        int gr = row0 + row;
        s16x8 v = (s16x8)0;
        if (gr < N) v = *(const s16x8*)(combin + (size_t)gr * 128 + seg * 8);
        *(s16x8*)(a_lds + dsts) = v;
        *(s16x8*)(b_lds + dsts) = *(const s16x8*)(Wzt + (size_t)row * 128 + seg * 8);
    }
    if (t < 64) { redS[t] = 0.f; redQ[t] = 0.f; }
    __syncthreads();
    int w = t >> 6, l = t & 63, hi = l >> 4, lo = l & 15;
    int ar = w * 16 + lo;
    s16x8 a[4];
#pragma unroll
    for (int kk = 0; kk < 4; ++kk) {
        int byte = (kk * 64 + hi * 16) ^ ((ar & 7) << 4);
        a[kk] = *(const s16x8*)(a_lds + ((ar * 256 + byte) >> 1));
    }
#pragma unroll
    for (int cf = 0; cf < 4; ++cf) {
        int br = cf * 16 + lo;
        f32x4 acc = (f32x4){0.f, 0.f, 0.f, 0.f};
#pragma unroll
        for (int kk = 0; kk < 4; ++kk) {
            int byte = (kk * 64 + hi * 16) ^ ((br & 7) << 4);
            s16x8 b = *(const s16x8*)(b_lds + ((br * 256 + byte) >> 1));
            acc = __builtin_amdgcn_mfma_f32_16x16x32_bf16(a[kk], b, acc, 0, 0, 0);
        }
        int colg = cf * 16 + lo;
        float bcv = bc[colg];
        float sv = 0.f, qv = 0.f;
#pragma unroll
        for (int r = 0; r < 4; ++r) {
            int rowg = row0 + w * 16 + hi * 4 + r;
            if (rowg < N) {
                float v = acc[r] + bcv;
                z[(size_t)rowg * 64 + colg] = v;
                sv += v; qv += v * v;
            }
        }
        atomicAdd(&redS[colg], sv);
        atomicAdd(&redQ[colg], qv);
    }
    __syncthreads();
    if (t < 64) {
        atomicAdd(&sums[t], redS[t]);
        atomicAdd(&sums[64 + t], redQ[t]);
    }
}

// Per-channel sum & sumsq for bf16 gout, C=512. uint4 loads; LDS reduce.
__global__ __launch_bounds__(256) void k_statsg(const uint4* __restrict__ X,
                                                float* __restrict__ sums, int N) {
    __shared__ float redS[512], redQ[512];
    int t = threadIdx.x;
    for (int i = t; i < 512; i += 256) { redS[i] = 0.f; redQ[i] = 0.f; }
    __syncthreads();
    int qu = t & 63;
    int slice = (blockIdx.x << 2) | (t >> 6);
    int nsl = gridDim.x << 2;
    float s[8], q[8];
#pragma unroll
    for (int j = 0; j < 8; ++j) { s[j] = 0.f; q[j] = 0.f; }
    for (int n = slice; n < N; n += nsl) {
        uint4 u = X[(size_t)n * 64 + qu];
        unsigned uu[4] = {u.x, u.y, u.z, u.w};
#pragma unroll
        for (int k2 = 0; k2 < 4; ++k2) {
            float a = bf_lo(uu[k2]), b = bf_hi(uu[k2]);
            s[2 * k2] += a; q[2 * k2] += a * a;
            s[2 * k2 + 1] += b; q[2 * k2 + 1] += b * b;
        }
    }
#pragma unroll
    for (int j = 0; j < 8; ++j) {
        atomicAdd(&redS[qu * 8 + j], s[j]);
        atomicAdd(&redQ[qu * 8 + j], q[j]);
    }
    __syncthreads();
    for (int i = t; i < 512; i += 256) {
        atomicAdd(&sums[i], redS[i]);
        atomicAdd(&sums[512 + i], redQ[i]);
    }
}

// sc[k] = g/sqrt(var+eps), sh[k] = be - mean*sc.
__global__ void k_bnparam(const float* __restrict__ sums, const float* __restrict__ g,
                          const float* __restrict__ be, float* __restrict__ sc,
                          float* __restrict__ sh, int N, int C) {
    int k = blockIdx.x * blockDim.x + threadIdx.x;
    if (k >= C) return;
    float invN = 1.0f / (float)N;
    float mean = sums[k] * invN;
    float var = sums[C + k] * invN - mean * mean;
    float s = g[k] * rsqrtf(var + 1e-5f);
    sc[k] = s;
    sh[k] = be[k] - mean * s;
}

// combin[n][0:64] = bf16(relu(z*sc+sh)), 4 ch/thread, uint2 stores.
__global__ void k_comb2(const float* __restrict__ z, const float* __restrict__ sc,
                        const float* __restrict__ sh, unsigned* __restrict__ combin32,
                        int N) {
    int idx = blockIdx.x * blockDim.x + threadIdx.x;
    if (idx >= N * 16) return;
    int n = idx >> 4, kq = idx & 15;
    float4 zv = *(const float4*)(z + (size_t)n * 64 + kq * 4);
    float v0 = fmaxf(fmaf(zv.x, sc[kq * 4 + 0], sh[kq * 4 + 0]), 0.f);
    float v1 = fmaxf(fmaf(zv.y, sc[kq * 4 + 1], sh[kq * 4 + 1]), 0.f);
    float v2 = fmaxf(fmaf(zv.z, sc[kq * 4 + 2], sh[kq * 4 + 2]), 0.f);
    float v3 = fmaxf(fmaf(zv.w, sc[kq * 4 + 3], sh[kq * 4 + 3]), 0.f);
    unsigned lo = (unsigned)f2bf(v0) | ((unsigned)f2bf(v1) << 16);
    unsigned hi = (unsigned)f2bf(v2) | ((unsigned)f2bf(v3) << 16);
    *(uint2*)(combin32 + (size_t)n * 64 + kq * 2) = make_uint2(lo, hi);
}

// ---- parallel exclusive scan of cntI -> rowptr (3 kernels) ----
__global__ void k_bsum(const int* __restrict__ cntI, int* __restrict__ bsum, int N) {
    int b = blockIdx.x, t = threadIdx.x;
    int base = b * 1024 + t * 4;
    int s = 0;
#pragma unroll
    for (int j = 0; j < 4; ++j) { int i = base + j; if (i < N) s += cntI[i]; }
    for (int off = 32; off; off >>= 1) s += __shfl_xor(s, off, 64);
    __shared__ int wsum[4];
    if ((t & 63) == 0) wsum[t >> 6] = s;
    __syncthreads();
    if (t == 0) bsum[b] = wsum[0] + wsum[1] + wsum[2] + wsum[3];
}
__global__ void k_boff(const int* __restrict__ bsum, int* __restrict__ boff, int nb) {
    int t = threadIdx.x;
    if (t < nb) { int s = 0; for (int j = 0; j < t; ++j) s += bsum[j]; boff[t] = s; }
}
__global__ void k_scan2(const int* __restrict__ cntI, const int* __restrict__ boff,
                        int* __restrict__ rowptr, int N) {
    int b = blockIdx.x, t = threadIdx.x;
    int base = b * 1024 + t * 4;
    int v[4]; int s = 0;
#pragma unroll
    for (int j = 0; j < 4; ++j) { int i = base + j; v[j] = (i < N) ? cntI[i] : 0; s += v[j]; }
    __shared__ int ls[256];
    ls[t] = s; __syncthreads();
    for (int off = 1; off < 256; off <<= 1) {
        int tv = (t >= (int)off) ? ls[t - off] : 0;
        __syncthreads(); ls[t] += tv; __syncthreads();
    }
    int run = ls[t] - s + boff[b];
#pragma unroll
    for (int j = 0; j < 4; ++j) { run += v[j]; int i = base + j; if (i < N) rowptr[i + 1] = run; }
    if (b == 0 && t == 0) rowptr[0] = 0;
}

// Scatter edge sources into CSR order (order within a segment is arbitrary).
__global__ void k_fill(const int* __restrict__ ei, const int* __restrict__ rowptr,
                       int* __restrict__ cursor, int* __restrict__ esrc, int E) {
    int e = blockIdx.x * blockDim.x + threadIdx.x;
    if (e >= E) return;
    int dst = ei[E + e];
    int pos = rowptr[dst] + atomicAdd(&cursor[dst], 1);
    esrc[pos] = ei[e];
}

// Wt[c][k] = bf16(c<512 ? W_l[k][c] : W_r[k][c-512]); [1024][128] bf16.
__global__ void k_prep_w(const float* __restrict__ Wl, const float* __restrict__ Wr,
                         unsigned short* __restrict__ Wt) {
    int idx = blockIdx.x * blockDim.x + threadIdx.x;
    if (idx >= 1024 * 128) return;
    int c = idx >> 7, k = idx & 127;
    float v = (c < 512) ? Wl[(size_t)k * 512 + c] : Wr[(size_t)k * 512 + (c - 512)];
    Wt[idx] = f2bf(v);
}

// Wp1t[c][k] = bf16(W_p1[k][c]); [64][512] bf16.
__global__ void k_prep_w1(const float* __restrict__ Wp1, unsigned short* __restrict__ Wp1t) {
    int idx = blockIdx.x * blockDim.x + threadIdx.x;
    if (idx >= 64 * 512) return;
    int c = idx >> 9, k = idx & 511;
    Wp1t[idx] = f2bf(Wp1[(size_t)k * 64 + c]);
}

// MFMA GEMM2: xlr[N][1024] = combin[N][128] @ Wt^T (bf16 out). 64 rows x 256 cols.
__global__ __launch_bounds__(256) void k_xlxr2(
    const unsigned short* __restrict__ combin, const unsigned short* __restrict__ Wt,
    unsigned short* __restrict__ xlr, int N) {
    __shared__ unsigned short a_lds[64 * 128];
    __shared__ unsigned short b_lds[256 * 128];
    int t = threadIdx.x;
    int row0 = blockIdx.x * 64;
    int c0 = blockIdx.y * 256;
    for (int i = t; i < 1024; i += 256) {
        int row = i >> 4, seg = i & 15;
        int dsts = (row * 256 + ((seg * 16) ^ ((row & 7) << 4))) >> 1;
        int gr = row0 + row;
        s16x8 v = (s16x8)0;
        if (gr < N) v = *(const s16x8*)(combin + (size_t)gr * 128 + seg * 8);
        *(s16x8*)(a_lds + dsts) = v;
    }
    for (int i = t; i < 4096; i += 256) {
        int row = i >> 4, seg = i & 15;
        int dsts = (row * 256 + ((seg * 16) ^ ((row & 7) << 4))) >> 1;
        *(s16x8*)(b_lds + dsts) = *(const s16x8*)(Wt + (size_t)(c0 + row) * 128 + seg * 8);
    }
    __syncthreads();
    int w = t >> 6, l = t & 63, hi = l >> 4, lo = l & 15;
    int ar = w * 16 + lo;
    s16x8 a[4];
#pragma unroll
    for (int kk = 0; kk < 4; ++kk) {
        int byte = (kk * 64 + hi * 16) ^ ((ar & 7) << 4);
        a[kk] = *(const s16x8*)(a_lds + ((ar * 256 + byte) >> 1));
    }
#pragma unroll
    for (int cf = 0; cf < 16; ++cf) {
        int br = cf * 16 + lo;
        f32x4 acc = (f32x4){0.f, 0.f, 0.f, 0.f};
#pragma unroll
        for (int kk = 0; kk < 4; ++kk) {
            int byte = (kk * 64 + hi * 16) ^ ((br & 7) << 4);
            s16x8 b = *(const s16x8*)(b_lds + ((br * 256 + byte) >> 1));
            acc = __builtin_amdgcn_mfma_f32_16x16x32_bf16(a[kk], b, acc, 0, 0, 0);
        }
        int colg = c0 + cf * 16 + lo;
#pragma unroll
        for (int r = 0; r < 4; ++r) {
            int rowg = row0 + w * 16 + hi * 4 + r;
            if (rowg < N) xlr[(size_t)rowg * 1024 + colg] = f2bf(acc[r]);
        }
    }
}

// GATv2 per-dst softmax (no max subtraction: |score| <~ 3 for this data scale,
// softmax is shift-invariant so result is mathematically identical) +
// weighted aggregation, 2-edge unrolled. One wave per dst node.
__global__ __launch_bounds__(256) void k_gat(
    const unsigned short* __restrict__ xlr, unsigned* __restrict__ gout32,
    const int* __restrict__ rowptr, const int* __restrict__ esrc,
    const float* __restrict__ att, const float* __restrict__ bg, int N) {
    int wid = (blockIdx.x * blockDim.x + threadIdx.x) >> 6;
    int lane = threadIdx.x & 63;
    if (wid >= N) return;
    int n = wid;
    float xrv[8], av[8], acc[8];
    {
        uint4 u = *(const uint4*)(xlr + (size_t)n * 1024 + 512 + lane * 8);
        unp8(u, xrv);
    }
#pragma unroll
    for (int j = 0; j < 8; ++j) { av[j] = att[lane * 8 + j]; acc[j] = 0.f; }
    float s = 0.f;
    int e0 = rowptr[n], e1 = rowptr[n + 1];
    int m = e1 - e0 + 1;                 // real edges + self loop
    int i = 0;
    for (; i + 2 <= m; i += 2) {
        int ia = e0 + i, ib = e0 + i + 1;
        int s0 = (ia < e1) ? esrc[ia] : n;
        int s1 = (ib < e1) ? esrc[ib] : n;
        uint4 u0 = *(const uint4*)(xlr + (size_t)s0 * 1024 + lane * 8);
        uint4 u1 = *(const uint4*)(xlr + (size_t)s1 * 1024 + lane * 8);
        float xlv0[8], xlv1[8];
        unp8(u0, xlv0); unp8(u1, xlv1);
        float ps0 = 0.f, ps1 = 0.f;
#pragma unroll
        for (int j = 0; j < 8; ++j) {
            float t0 = xlv0[j] + xrv[j];
            float t1 = xlv1[j] + xrv[j];
            t0 = fmaf(0.4f, fabsf(t0), 0.6f * t0);   // leaky_relu(t, 0.2)
            t1 = fmaf(0.4f, fabsf(t1), 0.6f * t1);
            ps0 = fmaf(t0, av[j], ps0);
            ps1 = fmaf(t1, av[j], ps1);
        }
        ps0 += __shfl_xor(ps0, 1, 64); ps1 += __shfl_xor(ps1, 1, 64);
        ps0 += __shfl_xor(ps0, 2, 64); ps1 += __shfl_xor(ps1, 2, 64);
        ps0 += __shfl_xor(ps0, 4, 64); ps1 += __shfl_xor(ps1, 4, 64);
        float w0 = __expf(ps0), w1 = __expf(ps1);
        s += w0 + w1;
#pragma unroll
        for (int j = 0; j < 8; ++j) {
            acc[j] = fmaf(w0, xlv0[j], acc[j]);
            acc[j] = fmaf(w1, xlv1[j], acc[j]);
        }
    }
    if (i < m) {
        int ia = e0 + i;
        int s0 = (ia < e1) ? esrc[ia] : n;
        uint4 u0 = *(const uint4*)(xlr + (size_t)s0 * 1024 + lane * 8);
        float xlv0[8];
        unp8(u0, xlv0);
        float ps0 = 0.f;
#pragma unroll
        for (int j = 0; j < 8; ++j) {
            float t0 = xlv0[j] + xrv[j];
            t0 = fmaf(0.4f, fabsf(t0), 0.6f * t0);
            ps0 = fmaf(t0, av[j], ps0);
        }
        ps0 += __shfl_xor(ps0, 1, 64);
        ps0 += __shfl_xor(ps0, 2, 64);
        ps0 += __shfl_xor(ps0, 4, 64);
        float w0 = __expf(ps0);
        s += w0;
#pragma unroll
        for (int j = 0; j < 8; ++j) acc[j] = fmaf(w0, xlv0[j], acc[j]);
    }
    float invs = 1.0f / s;
    unsigned o[4];
#pragma unroll
    for (int p = 0; p < 4; ++p) {
        float lo = acc[2 * p] * invs + bg[lane * 8 + 2 * p];
        float hi = acc[2 * p + 1] * invs + bg[lane * 8 + 2 * p + 1];
        o[p] = (unsigned)f2bf(lo) | ((unsigned)f2bf(hi) << 16);
    }
    *(uint4*)(gout32 + (size_t)n * 256 + lane * 4) = make_uint4(o[0], o[1], o[2], o[3]);
}

// MFMA post-GEMM: h1[N][64] = relu(bn(gout)) @ W_p1 + b_p1. BN folded to sc/sh.
// Fused: per-channel sum/sumsq of h1 into sums[0..64)/[64..128).
__global__ __launch_bounds__(256) void k_postm(
    const unsigned* __restrict__ gout32, const unsigned short* __restrict__ Wp1t,
    const float* __restrict__ sc, const float* __restrict__ sh,
    const float* __restrict__ bp1, float* __restrict__ h1, float* __restrict__ sums,
    int N) {
    __shared__ unsigned short a_lds[64 * 128];
    __shared__ unsigned short b_lds[64 * 128];
    __shared__ float sc_l[512], sh_l[512];
    __shared__ float redS[64], redQ[64];
    int t = threadIdx.x;
    for (int i = t; i < 512; i += 256) { sc_l[i] = sc[i]; sh_l[i] = sh[i]; }
    if (t < 64) { redS[t] = 0.f; redQ[t] = 0.f; }
    int row0 = blockIdx.x * 64;
    int w = t >> 6, l = t & 63, hi = l >> 4, lo = l & 15;
    int ar = w * 16 + lo;
    f32x4 acc[4];
#pragma unroll
    for (int cf = 0; cf < 4; ++cf) acc[cf] = (f32x4){0.f, 0.f, 0.f, 0.f};
    for (int kc = 0; kc < 4; ++kc) {
        __syncthreads();
        for (int i = t; i < 1024; i += 256) {
            int row = i >> 4, seg = i & 15;
            int dsts = (row * 256 + ((seg * 16) ^ ((row & 7) << 4))) >> 1;
            int gr = row0 + row;
            int k0 = kc * 128 + seg * 8;
            s16x8 v = (s16x8)0;
            if (gr < N) {
                uint4 u = *(const uint4*)(gout32 + (size_t)gr * 256 + (k0 >> 1));
                float f[8];
                unp8(u, f);
#pragma unroll
                for (int j = 0; j < 8; ++j) {
                    float y = fmaxf(fmaf(f[j], sc_l[k0 + j], sh_l[k0 + j]), 0.f);
                    v[j] = (short)f2bf(y);
                }
            }
            *(s16x8*)(a_lds + dsts) = v;
            *(s16x8*)(b_lds + dsts) = *(const s16x8*)(Wp1t + (size_t)row * 512 + k0);
        }
        __syncthreads();
        s16x8 a[4];
#pragma unroll
        for (int kk = 0; kk < 4; ++kk) {
            int byte = (kk * 64 + hi * 16) ^ ((ar & 7) << 4);
            a[kk] = *(const s16x8*)(a_lds + ((ar * 256 + byte) >> 1));
        }
#pragma unroll
        for (int cf = 0; cf < 4; ++cf) {
            int br = cf * 16 + lo;
#pragma unroll
            for (int kk = 0; kk < 4; ++kk) {
                int byte = (kk * 64 + hi * 16) ^ ((br & 7) << 4);
                s16x8 b = *(const s16x8*)(b_lds + ((br * 256 + byte) >> 1));
                acc[cf] = __builtin_amdgcn_mfma_f32_16x16x32_bf16(a[kk], b, acc[cf], 0, 0, 0);
            }
        }
    }
#pragma unroll
    for (int cf = 0; cf < 4; ++cf) {
        int colg = cf * 16 + lo;
        float bv = bp1[colg];
        float sv = 0.f, qv = 0.f;
#pragma unroll
        for (int r = 0; r < 4; ++r) {
            int rowg = row0 + w * 16 + hi * 4 + r;
            if (rowg < N) {
                float v = acc[cf][r] + bv;
                h1[(size_t)rowg * 64 + colg] = v;
                sv += v; qv += v * v;
            }
        }
        atomicAdd(&redS[colg], sv);
        atomicAdd(&redQ[colg], qv);
    }
    __syncthreads();
    if (t < 64) {
        atomicAdd(&sums[t], redS[t]);
        atomicAdd(&sums[64 + t], redQ[t]);
    }
}

// out[n] = relu(bn(h1 row)) . W_p2 + b_p2.  One wave per node.
__global__ void k_final(const float* __restrict__ h1, const float* __restrict__ stats,
                        const float* __restrict__ g, const float* __restrict__ be,
                        const float* __restrict__ Wp2, const float* __restrict__ bp2,
                        float* __restrict__ out, int N) {
    int wid = (blockIdx.x * blockDim.x + threadIdx.x) >> 6;
    int lane = threadIdx.x & 63;
    if (wid >= N) return;
    float invN = 1.0f / (float)N;
    float mean = stats[lane] * invN;
    float var = stats[64 + lane] * invN - mean * mean;
    float inv = rsqrtf(var + 1e-5f);
    float v = h1[(size_t)wid * 64 + lane];
    v = fmaxf((v - mean) * (inv * g[lane]) + be[lane], 0.f);
    float p = v * Wp2[lane];
#pragma unroll
    for (int off = 32; off; off >>= 1) p += __shfl_xor(p, off, 64);
    if (lane == 0) out[wid] = p + bp2[0];
}

extern "C" void kernel_launch(void* const* d_in, const int* in_sizes, int n_in,
                              void* d_out, int out_size, void* d_ws, size_t ws_size,
                              hipStream_t stream) {
    const float* x      = (const float*)d_in[0];
    const int*   ei     = (const int*)d_in[1];
    const float* ea     = (const float*)d_in[2];
    const float* W_ap   = (const float*)d_in[3];
    const float* b_ap   = (const float*)d_in[4];
    const float* W_ep   = (const float*)d_in[5];
    const float* b_ep   = (const float*)d_in[6];
    const float* W_msg  = (const float*)d_in[7];
    const float* b_msg  = (const float*)d_in[8];
    const float* g_msg  = (const float*)d_in[9];
    const float* be_msg = (const float*)d_in[10];
    const float* W_l    = (const float*)d_in[11];
    const float* W_r    = (const float*)d_in[12];
    const float* att    = (const float*)d_in[13];
    const float* b_gat  = (const float*)d_in[14];
    const float* g_bn   = (const float*)d_in[15];
    const float* be_bn  = (const float*)d_in[16];
    const float* W_p1   = (const float*)d_in[17];
    const float* b_p1   = (const float*)d_in[18];
    const float* g_p    = (const float*)d_in[19];
    const float* be_p   = (const float*)d_in[20];
    const float* W_p2   = (const float*)d_in[21];
    const float* b_p2   = (const float*)d_in[22];

    int N = in_sizes[0] / 64;
    int E = in_sizes[1] / 2;
    int nb = CDIV(N, 1024);

    // Workspace layout (floats). Zeroed prefix first.
    float* ws = (float*)d_ws;
    size_t off = 0;
    float* agg16  = ws + off; off += (size_t)N * 16;
    int*   cntI   = (int*)(ws + off); off += N;
    int*   cursor = (int*)(ws + off); off += N;
    float* st_msg = ws + off; off += 128;
    float* st_gat = ws + off; off += 1024;
    float* st_p   = ws + off; off += 128;
    size_t zero_floats = off;
    float* bn_sc  = ws + off; off += 512;
    float* bn_sh  = ws + off; off += 512;
    float* bn_sc2 = ws + off; off += 64;
    float* bn_sh2 = ws + off; off += 64;
    unsigned short* combin = (unsigned short*)(ws + off); off += (size_t)N * 64;  // N*128 bf16
    float* zb     = ws + off; off += (size_t)N * 64;       // z, later reused as h1
    unsigned short* Wzt = (unsigned short*)(ws + off); off += 4096;               // 64*128 bf16 = 4096 floats
    float* bc     = ws + off; off += 64;
    int*   rowptr = (int*)(ws + off); off += (size_t)(N + 1); off = (off + 3) & ~(size_t)3;
    int*   esrc   = (int*)(ws + off); off += E;
    int*   bsum   = (int*)(ws + off); off += 64;
    int*   boff   = (int*)(ws + off); off += 64;
    unsigned short* Wt  = (unsigned short*)(ws + off); off += 65536;              // 1024*128 bf16
    unsigned short* Wp1t = (unsigned short*)(ws + off); off += 16384;             // 64*512 bf16
    unsigned short* xlr = (unsigned short*)(ws + off); off += (size_t)N * 512;    // N*1024 bf16
    unsigned* gout32 = (unsigned*)(ws + off); off += (size_t)N * 256;             // N*512 bf16
    float* h1 = zb;

    hipMemsetAsync(d_ws, 0, zero_floats * sizeof(float), stream);

    k_prep_w<<<CDIV(1024 * 128, 256), 256, 0, stream>>>(W_l, W_r, Wt);
    k_prep_w1<<<CDIV(64 * 512, 256), 256, 0, stream>>>(W_p1, Wp1t);
    k_wc<<<1, 256, 0, stream>>>(W_ap, W_msg, b_ap, b_msg, Wzt, bc);
    k_scatter16<<<CDIV(E * 16, 256), 256, 0, stream>>>(ea, ei, agg16, cntI, E);
    k_combin<<<CDIV(N * 64, 256), 256, 0, stream>>>(x, agg16, cntI, W_ep, b_ep,
                                                    (unsigned*)combin, N);
    k_z<<<CDIV(N, 64), 256, 0, stream>>>(combin, Wzt, bc, zb, st_msg, N);
    k_bnparam<<<1, 64, 0, stream>>>(st_msg, g_msg, be_msg, bn_sc2, bn_sh2, N, 64);
    k_comb2<<<CDIV(N * 16, 256), 256, 0, stream>>>(zb, bn_sc2, bn_sh2,
                                                   (unsigned*)combin, N);
    k_bsum<<<nb, 256, 0, stream>>>(cntI, bsum, N);
    k_boff<<<1, 64, 0, stream>>>(bsum, boff, nb);
    k_scan2<<<nb, 256, 0, stream>>>(cntI, boff, rowptr, N);
    k_fill<<<CDIV(E, 256), 256, 0, stream>>>(ei, rowptr, cursor, esrc, E);
    dim3 gx(CDIV(N, 64), 4);
    k_xlxr2<<<gx, 256, 0, stream>>>(combin, Wt, xlr, N);
    k_gat<<<CDIV(N * 64, 256), 256, 0, stream>>>(xlr, gout32, rowptr, esrc, att, b_gat, N);
    k_statsg<<<256, 256, 0, stream>>>((const uint4*)gout32, st_gat, N);
    k_bnparam<<<2, 256, 0, stream>>>(st_gat, g_bn, be_bn, bn_sc, bn_sh, N, 512);
    k_postm<<<CDIV(N, 64), 256, 0, stream>>>(gout32, Wp1t, bn_sc, bn_sh, b_p1, h1, st_p, N);
    k_final<<<CDIV(N * 64, 256), 256, 0, stream>>>(h1, st_p, g_p, be_p, W_p2, b_p2,
                                                   (float*)d_out, N);
}